// Round 1
// baseline (1838.321 us; speedup 1.0000x reference)
//
#include <hip/hip_runtime.h>
#include <math.h>

#define BB   16
#define HHH  56
#define WWW  56
#define LL   3136      // 56*56
#define DIMM 128
#define DI_  128
#define KK   4
#define RR   4

// workspace layout (floats)
#define OFF_XI   ((size_t)0)
#define OFF_ZS   ((size_t)6422528)          // B*L*DI
#define OFF_XC   ((size_t)12845056)
#define OFF_XDBL ((size_t)19267584)         // B*K*L*8
#define OFF_YSUM ((size_t)20873216)
#define YSUM_BYTES ((size_t)6422528*4)

__device__ __forceinline__ float sigmoidf_(float x) { return 1.0f / (1.0f + __expf(-x)); }

// ---------------- Kernel A: in_proj GEMM + split + silu(z) ----------------
// xz[m, n] = sum_k x[m,k] * Wp[n,k];  n<128 -> xi, n>=128 -> silu -> zs
__global__ __launch_bounds__(256) void k_inproj(const float* __restrict__ x,
                                                const float* __restrict__ Wp,
                                                float* __restrict__ xi,
                                                float* __restrict__ zs)
{
    __shared__ float As[128 * 64];
    __shared__ float Ws[128 * 64];
    const int tid  = threadIdx.x;
    const int row0 = blockIdx.x * 64;
    const int col0 = blockIdx.y * 64;

    {   // stage tiles, transposed to [k][row]
        const int r  = tid & 63;
        const int cg = tid >> 6;
#pragma unroll
        for (int i = 0; i < 8; ++i) {
            const int k0 = cg * 4 + i * 16;
            float4 v = *(const float4*)&x[(size_t)(row0 + r) * 128 + k0];
            As[(k0 + 0) * 64 + r] = v.x;
            As[(k0 + 1) * 64 + r] = v.y;
            As[(k0 + 2) * 64 + r] = v.z;
            As[(k0 + 3) * 64 + r] = v.w;
            float4 u = *(const float4*)&Wp[(size_t)(col0 + r) * 128 + k0];
            Ws[(k0 + 0) * 64 + r] = u.x;
            Ws[(k0 + 1) * 64 + r] = u.y;
            Ws[(k0 + 2) * 64 + r] = u.z;
            Ws[(k0 + 3) * 64 + r] = u.w;
        }
    }
    __syncthreads();

    const int tx = tid & 15;   // col group
    const int ty = tid >> 4;   // row group
    float acc[4][4];
#pragma unroll
    for (int i = 0; i < 4; ++i)
#pragma unroll
        for (int j = 0; j < 4; ++j) acc[i][j] = 0.0f;

#pragma unroll 4
    for (int kk = 0; kk < 128; ++kk) {
        float4 a4 = *(const float4*)&As[kk * 64 + ty * 4];
        float4 b4 = *(const float4*)&Ws[kk * 64 + tx * 4];
        const float a[4] = {a4.x, a4.y, a4.z, a4.w};
        const float b[4] = {b4.x, b4.y, b4.z, b4.w};
#pragma unroll
        for (int i = 0; i < 4; ++i)
#pragma unroll
            for (int j = 0; j < 4; ++j) acc[i][j] = fmaf(a[i], b[j], acc[i][j]);
    }

#pragma unroll
    for (int i = 0; i < 4; ++i) {
        const size_t row = row0 + ty * 4 + i;
#pragma unroll
        for (int j = 0; j < 4; ++j) {
            const int col = col0 + tx * 4 + j;
            const float v = acc[i][j];
            if (col < 128) {
                xi[row * 128 + col] = v;
            } else {
                zs[row * 128 + (col - 128)] = v * sigmoidf_(v);
            }
        }
    }
}

// ---------------- Kernel B: depthwise 3x3 conv + bias + silu ----------------
__global__ __launch_bounds__(256) void k_conv(const float* __restrict__ xi,
                                              const float* __restrict__ cw,
                                              const float* __restrict__ cb,
                                              float* __restrict__ xc)
{
    const size_t idx = (size_t)blockIdx.x * 256 + threadIdx.x;
    if (idx >= (size_t)BB * LL * DI_) return;
    const int d    = idx & 127;
    const int rest = (int)(idx >> 7);
    const int p    = rest % LL;
    const int b    = rest / LL;
    const int h    = p / WWW;
    const int w    = p % WWW;

    float acc = cb[d];
#pragma unroll
    for (int dh = -1; dh <= 1; ++dh) {
        const int hh = h + dh;
        if (hh < 0 || hh >= HHH) continue;
#pragma unroll
        for (int dw = -1; dw <= 1; ++dw) {
            const int ww = w + dw;
            if (ww < 0 || ww >= WWW) continue;
            const float xv = xi[((size_t)b * LL + hh * WWW + ww) * 128 + d];
            acc = fmaf(xv, cw[d * 9 + (dh + 1) * 3 + (dw + 1)], acc);
        }
    }
    xc[idx] = acc * sigmoidf_(acc);
}

// ---------------- Kernel C: x_dbl projection (6 dots of 128 per (b,k,l)) ----------------
__global__ __launch_bounds__(256) void k_proj(const float* __restrict__ xc,
                                              const float* __restrict__ xpw,
                                              float* __restrict__ xdbl)
{
    const int wid  = threadIdx.x >> 6;
    const int lane = threadIdx.x & 63;
    const int bk    = blockIdx.x / (LL / 4);
    const int lbase = (blockIdx.x % (LL / 4)) * 4;
    const int b = bk >> 2;
    const int k = bk & 3;
    const int l = lbase + wid;

    int p;
    if (k == 0)      p = l;
    else if (k == 1) p = LL - 1 - l;
    else if (k == 2) p = (l % HHH) * WWW + (l / HHH);
    else             { const int l2 = LL - 1 - l; p = (l2 % HHH) * WWW + (l2 / HHH); }

    const float xv0 = xc[((size_t)b * LL + p) * 128 + lane];
    const float xv1 = xc[((size_t)b * LL + p) * 128 + lane + 64];

    float res[6];
#pragma unroll
    for (int c = 0; c < 6; ++c) {
        const float w0 = xpw[(k * 6 + c) * 128 + lane];
        const float w1 = xpw[(k * 6 + c) * 128 + lane + 64];
        float s = xv0 * w0 + xv1 * w1;
#pragma unroll
        for (int off = 32; off >= 1; off >>= 1) s += __shfl_xor(s, off, 64);
        res[c] = s;
    }
    if (lane == 0) {
        float* o = &xdbl[((size_t)bk * LL + l) * 8];
#pragma unroll
        for (int c = 0; c < 6; ++c) o[c] = res[c];
    }
}

// ---------------- Kernel D: the scan ----------------
// one block per (b,k); 128 threads, one per d; 3136 sequential steps
__global__ __launch_bounds__(128) void k_scan(const float* __restrict__ xc,
                                              const float* __restrict__ xdbl,
                                              const float* __restrict__ dtw_g,
                                              const float* __restrict__ dtb_g,
                                              const float* __restrict__ alog,
                                              const float* __restrict__ ds_g,
                                              float* __restrict__ ysum)
{
    const int bk = blockIdx.x;
    const int b  = bk >> 2;
    const int k  = bk & 3;
    const int d  = threadIdx.x;

    float dtw0 = dtw_g[(k * 128 + d) * 4 + 0];
    float dtw1 = dtw_g[(k * 128 + d) * 4 + 1];
    float dtw2 = dtw_g[(k * 128 + d) * 4 + 2];
    float dtw3 = dtw_g[(k * 128 + d) * 4 + 3];
    const float dtb  = dtb_g[k * 128 + d];
    const float Aneg = -__expf(alog[k * 128 + d]);
    const float Dd   = ds_g[k * 128 + d];

    const float* xd = &xdbl[(size_t)bk * LL * 8];
    const float* xcb = &xc[(size_t)b * LL * 128];
    float* yb = &ysum[(size_t)b * LL * 128];

    float h = 0.0f;
    for (int l = 0; l < LL; ++l) {
        int p;
        if (k == 0)      p = l;
        else if (k == 1) p = LL - 1 - l;
        else if (k == 2) p = (l % HHH) * WWW + (l / HHH);
        else             { const int l2 = LL - 1 - l; p = (l2 % HHH) * WWW + (l2 / HHH); }

        const float pr0 = xd[l * 8 + 0];
        const float pr1 = xd[l * 8 + 1];
        const float pr2 = xd[l * 8 + 2];
        const float pr3 = xd[l * 8 + 3];
        const float Bv  = xd[l * 8 + 4];
        const float Cv  = xd[l * 8 + 5];
        const float xv  = xcb[(size_t)p * 128 + d];

        float draw = fmaf(pr0, dtw0, fmaf(pr1, dtw1, fmaf(pr2, dtw2, fmaf(pr3, dtw3, dtb))));
        float dt = (draw > 20.0f) ? draw : log1pf(__expf(draw));
        const float dA  = __expf(dt * Aneg);
        const float dBu = dt * Bv * xv;
        h = fmaf(dA, h, dBu);
        const float y = fmaf(h, Cv, Dd * xv);
        atomicAdd(&yb[(size_t)p * 128 + d], y);
    }
}

// ---------------- Kernel E: LayerNorm + gate + spatial mean ----------------
__global__ __launch_bounds__(256) void k_final(const float* __restrict__ ysum,
                                               const float* __restrict__ zs,
                                               const float* __restrict__ onw,
                                               const float* __restrict__ onb,
                                               float* __restrict__ out)
{
    const int wid  = threadIdx.x >> 6;
    const int lane = threadIdx.x & 63;
    const int b     = blockIdx.x / 49;
    const int chunk = blockIdx.x % 49;
    const int pbase = chunk * 64 + wid * 16;

    const float w0 = onw[lane], w1 = onw[lane + 64];
    const float b0 = onb[lane], b1 = onb[lane + 64];

    float acc0 = 0.0f, acc1 = 0.0f;
    for (int i = 0; i < 16; ++i) {
        const int p = pbase + i;
        const float v0 = ysum[((size_t)b * LL + p) * 128 + lane];
        const float v1 = ysum[((size_t)b * LL + p) * 128 + lane + 64];
        float s = v0 + v1;
#pragma unroll
        for (int off = 32; off >= 1; off >>= 1) s += __shfl_xor(s, off, 64);
        const float mu = s * (1.0f / 128.0f);
        const float d0 = v0 - mu, d1 = v1 - mu;
        float sq = d0 * d0 + d1 * d1;
#pragma unroll
        for (int off = 32; off >= 1; off >>= 1) sq += __shfl_xor(sq, off, 64);
        const float rstd = rsqrtf(sq * (1.0f / 128.0f) + 1e-5f);
        const float yn0 = fmaf(d0 * rstd, w0, b0);
        const float yn1 = fmaf(d1 * rstd, w1, b1);
        const float g0 = zs[((size_t)b * LL + p) * 128 + lane];
        const float g1 = zs[((size_t)b * LL + p) * 128 + lane + 64];
        acc0 = fmaf(yn0, g0, acc0);
        acc1 = fmaf(yn1, g1, acc1);
    }
    atomicAdd(&out[b * 128 + lane],      acc0 * (1.0f / (float)LL));
    atomicAdd(&out[b * 128 + lane + 64], acc1 * (1.0f / (float)LL));
}

extern "C" void kernel_launch(void* const* d_in, const int* in_sizes, int n_in,
                              void* d_out, int out_size, void* d_ws, size_t ws_size,
                              hipStream_t stream)
{
    const float* x     = (const float*)d_in[0];
    const float* ipw   = (const float*)d_in[1];
    const float* cw    = (const float*)d_in[2];
    const float* cb    = (const float*)d_in[3];
    const float* xpw   = (const float*)d_in[4];
    const float* dtw   = (const float*)d_in[5];
    const float* dtb   = (const float*)d_in[6];
    const float* alog  = (const float*)d_in[7];
    const float* dsg   = (const float*)d_in[8];
    const float* onw   = (const float*)d_in[9];
    const float* onb   = (const float*)d_in[10];
    float* out = (float*)d_out;

    float* ws   = (float*)d_ws;
    float* xi   = ws + OFF_XI;
    float* zs   = ws + OFF_ZS;
    float* xc   = ws + OFF_XC;
    float* xdbl = ws + OFF_XDBL;
    float* ysum = ws + OFF_YSUM;

    hipMemsetAsync(ysum, 0, YSUM_BYTES, stream);
    hipMemsetAsync(out, 0, (size_t)out_size * 4, stream);

    // A: in_proj
    dim3 gA(784, 4);
    k_inproj<<<gA, 256, 0, stream>>>(x, ipw, xi, zs);

    // B: conv
    const size_t totB = (size_t)BB * LL * DI_;
    k_conv<<<(int)((totB + 255) / 256), 256, 0, stream>>>(xi, cw, cb, xc);

    // C: projection
    k_proj<<<BB * KK * (LL / 4), 256, 0, stream>>>(xc, xpw, xdbl);

    // D: scan
    k_scan<<<BB * KK, 128, 0, stream>>>(xc, xdbl, dtw, dtb, alog, dsg, ysum);

    // E: final
    k_final<<<BB * 49, 256, 0, stream>>>(ysum, zs, onw, onb, out);
}

// Round 2
// 499.080 us; speedup vs baseline: 3.6834x; 3.6834x over previous
//
#include <hip/hip_runtime.h>
#include <math.h>

#define BB   16
#define HHH  56
#define WWW  56
#define LL   3136      // 56*56
#define DI_  128
#define KK   4
#define NCH  49        // chunks per (b,k)
#define CS   64        // chunk size; NCH*CS == LL

// workspace layout (floats)
#define OFF_XI   ((size_t)0)           // B*L*DI ; reused as YSUM after conv
#define OFF_ZS   ((size_t)6422528)
#define OFF_XC   ((size_t)12845056)
#define OFF_XDBL ((size_t)19267584)    // B*K*L*8
#define OFF_PA   ((size_t)20873216)    // B*K*NCH*128
#define OFF_HL   ((size_t)21274624)
#define OFF_H0   ((size_t)21676032)
#define YSUM_BYTES ((size_t)6422528*4)

__device__ __forceinline__ float sigmoidf_(float x) { return 1.0f / (1.0f + __expf(-x)); }

__device__ __forceinline__ int pmap(int k, int l) {
    if (k == 0) return l;
    if (k == 1) return LL - 1 - l;
    if (k == 2) return (l % HHH) * WWW + (l / HHH);
    const int l2 = LL - 1 - l;
    return (l2 % HHH) * WWW + (l2 / HHH);
}

// ---------------- Kernel A: in_proj GEMM + split + silu(z) ----------------
__global__ __launch_bounds__(256) void k_inproj(const float* __restrict__ x,
                                                const float* __restrict__ Wp,
                                                float* __restrict__ xi,
                                                float* __restrict__ zs)
{
    __shared__ float As[128 * 64];
    __shared__ float Ws[128 * 64];
    const int tid  = threadIdx.x;
    const int row0 = blockIdx.x * 64;
    const int col0 = blockIdx.y * 64;

    {
        const int r  = tid & 63;
        const int cg = tid >> 6;
#pragma unroll
        for (int i = 0; i < 8; ++i) {
            const int k0 = cg * 4 + i * 16;
            float4 v = *(const float4*)&x[(size_t)(row0 + r) * 128 + k0];
            As[(k0 + 0) * 64 + r] = v.x;
            As[(k0 + 1) * 64 + r] = v.y;
            As[(k0 + 2) * 64 + r] = v.z;
            As[(k0 + 3) * 64 + r] = v.w;
            float4 u = *(const float4*)&Wp[(size_t)(col0 + r) * 128 + k0];
            Ws[(k0 + 0) * 64 + r] = u.x;
            Ws[(k0 + 1) * 64 + r] = u.y;
            Ws[(k0 + 2) * 64 + r] = u.z;
            Ws[(k0 + 3) * 64 + r] = u.w;
        }
    }
    __syncthreads();

    const int tx = tid & 15;
    const int ty = tid >> 4;
    float acc[4][4];
#pragma unroll
    for (int i = 0; i < 4; ++i)
#pragma unroll
        for (int j = 0; j < 4; ++j) acc[i][j] = 0.0f;

#pragma unroll 4
    for (int kk = 0; kk < 128; ++kk) {
        float4 a4 = *(const float4*)&As[kk * 64 + ty * 4];
        float4 b4 = *(const float4*)&Ws[kk * 64 + tx * 4];
        const float a[4] = {a4.x, a4.y, a4.z, a4.w};
        const float b[4] = {b4.x, b4.y, b4.z, b4.w};
#pragma unroll
        for (int i = 0; i < 4; ++i)
#pragma unroll
            for (int j = 0; j < 4; ++j) acc[i][j] = fmaf(a[i], b[j], acc[i][j]);
    }

#pragma unroll
    for (int i = 0; i < 4; ++i) {
        const size_t row = row0 + ty * 4 + i;
#pragma unroll
        for (int j = 0; j < 4; ++j) {
            const int col = col0 + tx * 4 + j;
            const float v = acc[i][j];
            if (col < 128) {
                xi[row * 128 + col] = v;
            } else {
                zs[row * 128 + (col - 128)] = v * sigmoidf_(v);
            }
        }
    }
}

// ---------------- Kernel B: depthwise 3x3 conv + bias + silu ----------------
__global__ __launch_bounds__(256) void k_conv(const float* __restrict__ xi,
                                              const float* __restrict__ cw,
                                              const float* __restrict__ cb,
                                              float* __restrict__ xc)
{
    const size_t idx = (size_t)blockIdx.x * 256 + threadIdx.x;
    if (idx >= (size_t)BB * LL * DI_) return;
    const int d    = idx & 127;
    const int rest = (int)(idx >> 7);
    const int p    = rest % LL;
    const int b    = rest / LL;
    const int h    = p / WWW;
    const int w    = p % WWW;

    float acc = cb[d];
#pragma unroll
    for (int dh = -1; dh <= 1; ++dh) {
        const int hh = h + dh;
        if (hh < 0 || hh >= HHH) continue;
#pragma unroll
        for (int dw = -1; dw <= 1; ++dw) {
            const int ww = w + dw;
            if (ww < 0 || ww >= WWW) continue;
            const float xv = xi[((size_t)b * LL + hh * WWW + ww) * 128 + d];
            acc = fmaf(xv, cw[d * 9 + (dh + 1) * 3 + (dw + 1)], acc);
        }
    }
    xc[idx] = acc * sigmoidf_(acc);
}

// ---------------- Kernel C: x_dbl projection ----------------
__global__ __launch_bounds__(256) void k_proj(const float* __restrict__ xc,
                                              const float* __restrict__ xpw,
                                              float* __restrict__ xdbl)
{
    const int wid  = threadIdx.x >> 6;
    const int lane = threadIdx.x & 63;
    const int bk    = blockIdx.x / (LL / 4);
    const int lbase = (blockIdx.x % (LL / 4)) * 4;
    const int b = bk >> 2;
    const int k = bk & 3;
    const int l = lbase + wid;
    const int p = pmap(k, l);

    const float xv0 = xc[((size_t)b * LL + p) * 128 + lane];
    const float xv1 = xc[((size_t)b * LL + p) * 128 + lane + 64];

    float res[6];
#pragma unroll
    for (int c = 0; c < 6; ++c) {
        const float w0 = xpw[(k * 6 + c) * 128 + lane];
        const float w1 = xpw[(k * 6 + c) * 128 + lane + 64];
        float s = xv0 * w0 + xv1 * w1;
#pragma unroll
        for (int off = 32; off >= 1; off >>= 1) s += __shfl_xor(s, off, 64);
        res[c] = s;
    }
    if (lane == 0) {
        float* o = &xdbl[((size_t)bk * LL + l) * 8];
#pragma unroll
        for (int c = 0; c < 6; ++c) o[c] = res[c];
    }
}

// ---------------- Scan pass 1: per-chunk summaries ----------------
// grid: BB*KK*NCH blocks, 128 threads (one per d)
__global__ __launch_bounds__(128) void k_scan1(const float* __restrict__ xc,
                                               const float* __restrict__ xdbl,
                                               const float* __restrict__ dtw_g,
                                               const float* __restrict__ dtb_g,
                                               const float* __restrict__ alog,
                                               float* __restrict__ Pa,
                                               float* __restrict__ Hl)
{
    const int bk = blockIdx.x / NCH;
    const int c  = blockIdx.x % NCH;
    const int b  = bk >> 2;
    const int k  = bk & 3;
    const int d  = threadIdx.x;

    const float dtw0 = dtw_g[(k * 128 + d) * 4 + 0];
    const float dtw1 = dtw_g[(k * 128 + d) * 4 + 1];
    const float dtw2 = dtw_g[(k * 128 + d) * 4 + 2];
    const float dtw3 = dtw_g[(k * 128 + d) * 4 + 3];
    const float dtb  = dtb_g[k * 128 + d];
    const float Aneg = -__expf(alog[k * 128 + d]);

    const float* xd  = &xdbl[(size_t)bk * LL * 8];
    const float* xcb = &xc[(size_t)b * LL * 128];

    float P = 1.0f, h = 0.0f;
    const int l0 = c * CS;
    for (int i = 0; i < CS; ++i) {
        const int l = l0 + i;
        const int p = pmap(k, l);
        const float pr0 = xd[l * 8 + 0];
        const float pr1 = xd[l * 8 + 1];
        const float pr2 = xd[l * 8 + 2];
        const float pr3 = xd[l * 8 + 3];
        const float Bv  = xd[l * 8 + 4];
        const float xv  = xcb[(size_t)p * 128 + d];

        float draw = fmaf(pr0, dtw0, fmaf(pr1, dtw1, fmaf(pr2, dtw2, fmaf(pr3, dtw3, dtb))));
        float dt = (draw > 20.0f) ? draw : log1pf(__expf(draw));
        const float dA  = __expf(dt * Aneg);
        const float dBu = dt * Bv * xv;
        P *= dA;
        h = fmaf(dA, h, dBu);
    }
    Pa[(size_t)blockIdx.x * 128 + d] = P;
    Hl[(size_t)blockIdx.x * 128 + d] = h;
}

// ---------------- Scan pass 2: combine chunk summaries ----------------
// grid: BB*KK blocks, 128 threads
__global__ __launch_bounds__(128) void k_scan2(const float* __restrict__ Pa,
                                               const float* __restrict__ Hl,
                                               float* __restrict__ H0)
{
    const int bk = blockIdx.x;
    const int d  = threadIdx.x;
    float h = 0.0f;
    for (int c = 0; c < NCH; ++c) {
        const size_t o = ((size_t)bk * NCH + c) * 128 + d;
        H0[o] = h;
        h = fmaf(Pa[o], h, Hl[o]);
    }
}

// ---------------- Scan pass 3: recompute with correct h0, emit y ----------------
__global__ __launch_bounds__(128) void k_scan3(const float* __restrict__ xc,
                                               const float* __restrict__ xdbl,
                                               const float* __restrict__ dtw_g,
                                               const float* __restrict__ dtb_g,
                                               const float* __restrict__ alog,
                                               const float* __restrict__ ds_g,
                                               const float* __restrict__ H0,
                                               float* __restrict__ ysum)
{
    const int bk = blockIdx.x / NCH;
    const int c  = blockIdx.x % NCH;
    const int b  = bk >> 2;
    const int k  = bk & 3;
    const int d  = threadIdx.x;

    const float dtw0 = dtw_g[(k * 128 + d) * 4 + 0];
    const float dtw1 = dtw_g[(k * 128 + d) * 4 + 1];
    const float dtw2 = dtw_g[(k * 128 + d) * 4 + 2];
    const float dtw3 = dtw_g[(k * 128 + d) * 4 + 3];
    const float dtb  = dtb_g[k * 128 + d];
    const float Aneg = -__expf(alog[k * 128 + d]);
    const float Dd   = ds_g[k * 128 + d];

    const float* xd  = &xdbl[(size_t)bk * LL * 8];
    const float* xcb = &xc[(size_t)b * LL * 128];
    float* yb = &ysum[(size_t)b * LL * 128];

    float h = H0[(size_t)blockIdx.x * 128 + d];
    const int l0 = c * CS;
    for (int i = 0; i < CS; ++i) {
        const int l = l0 + i;
        const int p = pmap(k, l);
        const float pr0 = xd[l * 8 + 0];
        const float pr1 = xd[l * 8 + 1];
        const float pr2 = xd[l * 8 + 2];
        const float pr3 = xd[l * 8 + 3];
        const float Bv  = xd[l * 8 + 4];
        const float Cv  = xd[l * 8 + 5];
        const float xv  = xcb[(size_t)p * 128 + d];

        float draw = fmaf(pr0, dtw0, fmaf(pr1, dtw1, fmaf(pr2, dtw2, fmaf(pr3, dtw3, dtb))));
        float dt = (draw > 20.0f) ? draw : log1pf(__expf(draw));
        const float dA  = __expf(dt * Aneg);
        const float dBu = dt * Bv * xv;
        h = fmaf(dA, h, dBu);
        const float y = fmaf(h, Cv, Dd * xv);
        atomicAdd(&yb[(size_t)p * 128 + d], y);
    }
}

// ---------------- Kernel E: LayerNorm + gate + spatial mean ----------------
__global__ __launch_bounds__(256) void k_final(const float* __restrict__ ysum,
                                               const float* __restrict__ zs,
                                               const float* __restrict__ onw,
                                               const float* __restrict__ onb,
                                               float* __restrict__ out)
{
    const int wid  = threadIdx.x >> 6;
    const int lane = threadIdx.x & 63;
    const int b     = blockIdx.x / 49;
    const int chunk = blockIdx.x % 49;
    const int pbase = chunk * 64 + wid * 16;

    const float w0 = onw[lane], w1 = onw[lane + 64];
    const float b0 = onb[lane], b1 = onb[lane + 64];

    float acc0 = 0.0f, acc1 = 0.0f;
    for (int i = 0; i < 16; ++i) {
        const int p = pbase + i;
        const float v0 = ysum[((size_t)b * LL + p) * 128 + lane];
        const float v1 = ysum[((size_t)b * LL + p) * 128 + lane + 64];
        float s = v0 + v1;
#pragma unroll
        for (int off = 32; off >= 1; off >>= 1) s += __shfl_xor(s, off, 64);
        const float mu = s * (1.0f / 128.0f);
        const float d0 = v0 - mu, d1 = v1 - mu;
        float sq = d0 * d0 + d1 * d1;
#pragma unroll
        for (int off = 32; off >= 1; off >>= 1) sq += __shfl_xor(sq, off, 64);
        const float rstd = rsqrtf(sq * (1.0f / 128.0f) + 1e-5f);
        const float yn0 = fmaf(d0 * rstd, w0, b0);
        const float yn1 = fmaf(d1 * rstd, w1, b1);
        const float g0 = zs[((size_t)b * LL + p) * 128 + lane];
        const float g1 = zs[((size_t)b * LL + p) * 128 + lane + 64];
        acc0 = fmaf(yn0, g0, acc0);
        acc1 = fmaf(yn1, g1, acc1);
    }
    atomicAdd(&out[b * 128 + lane],      acc0 * (1.0f / (float)LL));
    atomicAdd(&out[b * 128 + lane + 64], acc1 * (1.0f / (float)LL));
}

extern "C" void kernel_launch(void* const* d_in, const int* in_sizes, int n_in,
                              void* d_out, int out_size, void* d_ws, size_t ws_size,
                              hipStream_t stream)
{
    const float* x     = (const float*)d_in[0];
    const float* ipw   = (const float*)d_in[1];
    const float* cw    = (const float*)d_in[2];
    const float* cb    = (const float*)d_in[3];
    const float* xpw   = (const float*)d_in[4];
    const float* dtw   = (const float*)d_in[5];
    const float* dtb   = (const float*)d_in[6];
    const float* alog  = (const float*)d_in[7];
    const float* dsg   = (const float*)d_in[8];
    const float* onw   = (const float*)d_in[9];
    const float* onb   = (const float*)d_in[10];
    float* out = (float*)d_out;

    float* ws   = (float*)d_ws;
    float* xi   = ws + OFF_XI;     // becomes ysum after conv
    float* zs   = ws + OFF_ZS;
    float* xc   = ws + OFF_XC;
    float* xdbl = ws + OFF_XDBL;
    float* Pa   = ws + OFF_PA;
    float* Hl   = ws + OFF_HL;
    float* H0   = ws + OFF_H0;
    float* ysum = xi;

    hipMemsetAsync(out, 0, (size_t)out_size * 4, stream);

    // A: in_proj
    dim3 gA(784, 4);
    k_inproj<<<gA, 256, 0, stream>>>(x, ipw, xi, zs);

    // B: conv (reads xi, writes xc)
    const size_t totB = (size_t)BB * LL * DI_;
    k_conv<<<(int)((totB + 255) / 256), 256, 0, stream>>>(xi, cw, cb, xc);

    // xi dead now -> zero it for use as ysum
    hipMemsetAsync(ysum, 0, YSUM_BYTES, stream);

    // C: projection
    k_proj<<<BB * KK * (LL / 4), 256, 0, stream>>>(xc, xpw, xdbl);

    // D: chunked scan
    k_scan1<<<BB * KK * NCH, 128, 0, stream>>>(xc, xdbl, dtw, dtb, alog, Pa, Hl);
    k_scan2<<<BB * KK, 128, 0, stream>>>(Pa, Hl, H0);
    k_scan3<<<BB * KK * NCH, 128, 0, stream>>>(xc, xdbl, dtw, dtb, alog, dsg, H0, ysum);

    // E: final
    k_final<<<BB * 49, 256, 0, stream>>>(ysum, zs, onw, onb, out);
}

// Round 3
// 381.371 us; speedup vs baseline: 4.8203x; 1.3086x over previous
//
#include <hip/hip_runtime.h>
#include <math.h>

#define BB   16
#define HHH  56
#define WWW  56
#define LL   3136      // 56*56
#define DI_  128
#define KK   4
#define NCH  98        // chunks per (b,k)
#define CS   32        // chunk size; NCH*CS == LL

// workspace layout (floats)
#define OFF_XI   ((size_t)0)           // B*L*DI ; reused as YSUM after convproj
#define OFF_ZS   ((size_t)6422528)
#define OFF_XC   ((size_t)12845056)
#define OFF_XDBL ((size_t)19267584)    // B*K*L*8 = 1605632
#define OFF_PA   ((size_t)20873216)    // B*K*NCH*128 = 802816
#define OFF_HL   ((size_t)21676032)
#define OFF_H0   ((size_t)22478848)

__device__ __forceinline__ float sigmoidf_(float x) { return 1.0f / (1.0f + __expf(-x)); }

// softplus, branchless, ~6 VALU ops, abs err ~1e-7
__device__ __forceinline__ float softplus_(float x) {
    return fmaxf(x, 0.0f) + __logf(1.0f + __expf(-fabsf(x)));
}

// ---------------- Kernel A: in_proj GEMM + split + silu(z) ----------------
// one block per 64-row tile; loops over all 4 col tiles (A staged once)
__global__ __launch_bounds__(256) void k_inproj(const float* __restrict__ x,
                                                const float* __restrict__ Wp,
                                                float* __restrict__ xi,
                                                float* __restrict__ zs)
{
    __shared__ float As[128 * 64];
    __shared__ float Ws[128 * 64];
    const int tid  = threadIdx.x;
    const int row0 = blockIdx.x * 64;
    const int r  = tid & 63;
    const int cg = tid >> 6;

    // stage A tile once, transposed to [k][row]
#pragma unroll
    for (int i = 0; i < 8; ++i) {
        const int k0 = cg * 4 + i * 16;
        float4 v = *(const float4*)&x[(size_t)(row0 + r) * 128 + k0];
        As[(k0 + 0) * 64 + r] = v.x;
        As[(k0 + 1) * 64 + r] = v.y;
        As[(k0 + 2) * 64 + r] = v.z;
        As[(k0 + 3) * 64 + r] = v.w;
    }

    const int tx = tid & 15;
    const int ty = tid >> 4;

    for (int cb = 0; cb < 4; ++cb) {
        const int col0 = cb * 64;
        __syncthreads();   // As ready / prev compute done
#pragma unroll
        for (int i = 0; i < 8; ++i) {
            const int k0 = cg * 4 + i * 16;
            float4 u = *(const float4*)&Wp[(size_t)(col0 + r) * 128 + k0];
            Ws[(k0 + 0) * 64 + r] = u.x;
            Ws[(k0 + 1) * 64 + r] = u.y;
            Ws[(k0 + 2) * 64 + r] = u.z;
            Ws[(k0 + 3) * 64 + r] = u.w;
        }
        __syncthreads();

        float acc[4][4];
#pragma unroll
        for (int i = 0; i < 4; ++i)
#pragma unroll
            for (int j = 0; j < 4; ++j) acc[i][j] = 0.0f;

#pragma unroll 4
        for (int kk = 0; kk < 128; ++kk) {
            float4 a4 = *(const float4*)&As[kk * 64 + ty * 4];
            float4 b4 = *(const float4*)&Ws[kk * 64 + tx * 4];
            const float a[4] = {a4.x, a4.y, a4.z, a4.w};
            const float b[4] = {b4.x, b4.y, b4.z, b4.w};
#pragma unroll
            for (int i = 0; i < 4; ++i)
#pragma unroll
                for (int j = 0; j < 4; ++j) acc[i][j] = fmaf(a[i], b[j], acc[i][j]);
        }

#pragma unroll
        for (int i = 0; i < 4; ++i) {
            const size_t row = row0 + ty * 4 + i;
#pragma unroll
            for (int j = 0; j < 4; ++j) {
                const int col = col0 + tx * 4 + j;
                const float v = acc[i][j];
                if (col < 128) {
                    xi[row * 128 + col] = v;
                } else {
                    zs[row * 128 + (col - 128)] = v * sigmoidf_(v);
                }
            }
        }
    }
}

// ---------------- Kernel B: fused depthwise conv3x3 + silu + x_proj ----------------
// one block per (b, 8x8 spatial tile); 256 threads
__global__ __launch_bounds__(256) void k_convproj(const float* __restrict__ xi,
                                                  const float* __restrict__ cw,
                                                  const float* __restrict__ cbias,
                                                  const float* __restrict__ xpw,
                                                  float* __restrict__ xc,
                                                  float* __restrict__ xdbl)
{
    __shared__ float xs_lds[64 * 129];
    __shared__ float w_lds[24 * 128];
    const int tid = threadIdx.x;
    const int b   = blockIdx.x / 49;
    const int t   = blockIdx.x % 49;
    const int h0  = (t / 7) * 8;
    const int w0  = (t % 7) * 8;

    // stage projection weights (K*6*128 = 3072 floats)
    for (int i = tid; i < 24 * 128; i += 256) w_lds[i] = xpw[i];

    // conv phase: 64 positions x 128 d = 8192 elems, 32 per thread
#pragma unroll 4
    for (int i = 0; i < 32; ++i) {
        const int idx = i * 256 + tid;
        const int d   = idx & 127;
        const int pi  = idx >> 7;
        const int hh  = h0 + (pi >> 3);
        const int ww  = w0 + (pi & 7);
        float acc = cbias[d];
#pragma unroll
        for (int dh = -1; dh <= 1; ++dh) {
            const int h = hh + dh;
            if (h < 0 || h >= HHH) continue;
#pragma unroll
            for (int dw = -1; dw <= 1; ++dw) {
                const int w = ww + dw;
                if (w < 0 || w >= WWW) continue;
                acc = fmaf(xi[((size_t)b * LL + h * WWW + w) * 128 + d],
                           cw[d * 9 + (dh + 1) * 3 + (dw + 1)], acc);
            }
        }
        const float v = acc * sigmoidf_(acc);
        xc[((size_t)b * LL + hh * WWW + ww) * 128 + d] = v;
        xs_lds[pi * 129 + d] = v;
    }
    __syncthreads();

    // proj phase: wave w -> direction k=w; lane -> position
    const int ks   = __builtin_amdgcn_readfirstlane(tid >> 6);
    const int lane = tid & 63;
    const int p    = (h0 + (lane >> 3)) * WWW + (w0 + (lane & 7));
    int l;
    if (ks == 0)      l = p;
    else if (ks == 1) l = LL - 1 - p;
    else if (ks == 2) l = (p % HHH) * WWW + (p / HHH);
    else              l = LL - 1 - ((p % HHH) * WWW + (p / HHH));

    float acc6[6] = {0.f, 0.f, 0.f, 0.f, 0.f, 0.f};
#pragma unroll 4
    for (int d = 0; d < 128; ++d) {
        const float xv = xs_lds[lane * 129 + d];
#pragma unroll
        for (int c = 0; c < 6; ++c)
            acc6[c] = fmaf(xv, w_lds[(ks * 6 + c) * 128 + d], acc6[c]);
    }
    float* o = &xdbl[((size_t)(b * 4 + ks) * LL + l) * 8];
#pragma unroll
    for (int c = 0; c < 6; ++c) o[c] = acc6[c];
}

__device__ __forceinline__ int pmap(int k, int l) {
    if (k == 0) return l;
    if (k == 1) return LL - 1 - l;
    if (k == 2) return (l % HHH) * WWW + (l / HHH);
    const int l2 = LL - 1 - l;
    return (l2 % HHH) * WWW + (l2 / HHH);
}

// ---------------- Scan pass 1: per-chunk summaries ----------------
__global__ __launch_bounds__(128) void k_scan1(const float* __restrict__ xc,
                                               const float* __restrict__ xdbl,
                                               const float* __restrict__ dtw_g,
                                               const float* __restrict__ dtb_g,
                                               const float* __restrict__ alog,
                                               float* __restrict__ Pa,
                                               float* __restrict__ Hl)
{
    __shared__ float xd_s[CS * 8];
    const int bk = blockIdx.x / NCH;
    const int c  = blockIdx.x % NCH;
    const int b  = bk >> 2;
    const int k  = bk & 3;
    const int d  = threadIdx.x;
    const int l0 = c * CS;

    const float* xd = &xdbl[((size_t)bk * LL + l0) * 8];
    xd_s[d]       = xd[d];
    xd_s[d + 128] = xd[d + 128];
    __syncthreads();

    const float dtw0 = dtw_g[(k * 128 + d) * 4 + 0];
    const float dtw1 = dtw_g[(k * 128 + d) * 4 + 1];
    const float dtw2 = dtw_g[(k * 128 + d) * 4 + 2];
    const float dtw3 = dtw_g[(k * 128 + d) * 4 + 3];
    const float dtb  = dtb_g[k * 128 + d];
    const float Aneg = -__expf(alog[k * 128 + d]);
    const float* xcb = &xc[(size_t)b * LL * 128];

    float P = 1.0f, h = 0.0f;
#pragma unroll 4
    for (int i = 0; i < CS; ++i) {
        const int p = pmap(k, l0 + i);
        const float xv  = xcb[(size_t)p * 128 + d];
        const float draw = fmaf(xd_s[i*8+0], dtw0, fmaf(xd_s[i*8+1], dtw1,
                           fmaf(xd_s[i*8+2], dtw2, fmaf(xd_s[i*8+3], dtw3, dtb))));
        const float dt  = softplus_(draw);
        const float dA  = __expf(dt * Aneg);
        const float dBu = dt * xd_s[i*8+4] * xv;
        P *= dA;
        h = fmaf(dA, h, dBu);
    }
    Pa[(size_t)blockIdx.x * 128 + d] = P;
    Hl[(size_t)blockIdx.x * 128 + d] = h;
}

// ---------------- Scan pass 2: combine chunk summaries ----------------
__global__ __launch_bounds__(128) void k_scan2(const float* __restrict__ Pa,
                                               const float* __restrict__ Hl,
                                               float* __restrict__ H0)
{
    const int bk = blockIdx.x;
    const int d  = threadIdx.x;
    float h = 0.0f;
    for (int c = 0; c < NCH; ++c) {
        const size_t o = ((size_t)bk * NCH + c) * 128 + d;
        H0[o] = h;
        h = fmaf(Pa[o], h, Hl[o]);
    }
}

// ---------------- Scan pass 3a: directions 0+1 paired, plain store ----------------
// block (b, c): k=0 chunk c and k=1 chunk NCH-1-c cover p in [CS*c, CS*c+CS)
__global__ __launch_bounds__(128) void k_scan3a(const float* __restrict__ xc,
                                                const float* __restrict__ xdbl,
                                                const float* __restrict__ dtw_g,
                                                const float* __restrict__ dtb_g,
                                                const float* __restrict__ alog,
                                                const float* __restrict__ ds_g,
                                                const float* __restrict__ H0,
                                                float* __restrict__ ysum)
{
    __shared__ float xd0_s[CS * 8];
    __shared__ float xd1_s[CS * 8];
    const int b = blockIdx.x / NCH;
    const int c = blockIdx.x % NCH;
    const int d = threadIdx.x;
    const int c2 = NCH - 1 - c;
    const int bk0 = b * 4 + 0, bk1 = b * 4 + 1;
    const int l0a = c * CS, l0b = c2 * CS;

    {
        const float* xda = &xdbl[((size_t)bk0 * LL + l0a) * 8];
        const float* xdb = &xdbl[((size_t)bk1 * LL + l0b) * 8];
        xd0_s[d]       = xda[d];
        xd0_s[d + 128] = xda[d + 128];
        xd1_s[d]       = xdb[d];
        xd1_s[d + 128] = xdb[d + 128];
    }
    __syncthreads();

    const float* xcb = &xc[(size_t)b * LL * 128];
    float* yb = &ysum[(size_t)b * LL * 128];

    float xv[CS];
#pragma unroll
    for (int i = 0; i < CS; ++i) xv[i] = xcb[(size_t)(l0a + i) * 128 + d];

    float y[CS];

    // k = 0: p = l = l0a + i
    {
        const float dtw0 = dtw_g[(0 * 128 + d) * 4 + 0];
        const float dtw1 = dtw_g[(0 * 128 + d) * 4 + 1];
        const float dtw2 = dtw_g[(0 * 128 + d) * 4 + 2];
        const float dtw3 = dtw_g[(0 * 128 + d) * 4 + 3];
        const float dtb  = dtb_g[0 * 128 + d];
        const float Aneg = -__expf(alog[0 * 128 + d]);
        const float Dd   = ds_g[0 * 128 + d];
        float h = H0[((size_t)bk0 * NCH + c) * 128 + d];
#pragma unroll
        for (int i = 0; i < CS; ++i) {
            const float draw = fmaf(xd0_s[i*8+0], dtw0, fmaf(xd0_s[i*8+1], dtw1,
                               fmaf(xd0_s[i*8+2], dtw2, fmaf(xd0_s[i*8+3], dtw3, dtb))));
            const float dt  = softplus_(draw);
            const float dA  = __expf(dt * Aneg);
            h = fmaf(dA, h, dt * xd0_s[i*8+4] * xv[i]);
            y[i] = fmaf(h, xd0_s[i*8+5], Dd * xv[i]);
        }
    }
    // k = 1: step i -> p-window index (CS-1-i)
    {
        const float dtw0 = dtw_g[(1 * 128 + d) * 4 + 0];
        const float dtw1 = dtw_g[(1 * 128 + d) * 4 + 1];
        const float dtw2 = dtw_g[(1 * 128 + d) * 4 + 2];
        const float dtw3 = dtw_g[(1 * 128 + d) * 4 + 3];
        const float dtb  = dtb_g[1 * 128 + d];
        const float Aneg = -__expf(alog[1 * 128 + d]);
        const float Dd   = ds_g[1 * 128 + d];
        float h = H0[((size_t)bk1 * NCH + c2) * 128 + d];
#pragma unroll
        for (int i = 0; i < CS; ++i) {
            const int j = CS - 1 - i;
            const float draw = fmaf(xd1_s[i*8+0], dtw0, fmaf(xd1_s[i*8+1], dtw1,
                               fmaf(xd1_s[i*8+2], dtw2, fmaf(xd1_s[i*8+3], dtw3, dtb))));
            const float dt  = softplus_(draw);
            const float dA  = __expf(dt * Aneg);
            h = fmaf(dA, h, dt * xd1_s[i*8+4] * xv[j]);
            y[j] += fmaf(h, xd1_s[i*8+5], Dd * xv[j]);
        }
    }
#pragma unroll
    for (int i = 0; i < CS; ++i)
        yb[(size_t)(l0a + i) * 128 + d] = y[i];
}

// ---------------- Scan pass 3b: directions 2+3 paired, atomic add ----------------
__global__ __launch_bounds__(128) void k_scan3b(const float* __restrict__ xc,
                                                const float* __restrict__ xdbl,
                                                const float* __restrict__ dtw_g,
                                                const float* __restrict__ dtb_g,
                                                const float* __restrict__ alog,
                                                const float* __restrict__ ds_g,
                                                const float* __restrict__ H0,
                                                float* __restrict__ ysum)
{
    __shared__ float xd0_s[CS * 8];
    __shared__ float xd1_s[CS * 8];
    const int b = blockIdx.x / NCH;
    const int c = blockIdx.x % NCH;
    const int d = threadIdx.x;
    const int c2 = NCH - 1 - c;
    const int bk2 = b * 4 + 2, bk3 = b * 4 + 3;
    const int l0a = c * CS, l0b = c2 * CS;

    {
        const float* xda = &xdbl[((size_t)bk2 * LL + l0a) * 8];
        const float* xdb = &xdbl[((size_t)bk3 * LL + l0b) * 8];
        xd0_s[d]       = xda[d];
        xd0_s[d + 128] = xda[d + 128];
        xd1_s[d]       = xdb[d];
        xd1_s[d + 128] = xdb[d + 128];
    }
    __syncthreads();

    const float* xcb = &xc[(size_t)b * LL * 128];
    float* yb = &ysum[(size_t)b * LL * 128];

    int pj[CS];
#pragma unroll
    for (int i = 0; i < CS; ++i) {
        const int l = l0a + i;
        pj[i] = (l % HHH) * WWW + (l / HHH);
    }
    float xv[CS];
#pragma unroll
    for (int i = 0; i < CS; ++i) xv[i] = xcb[(size_t)pj[i] * 128 + d];

    float y[CS];

    // k = 2
    {
        const float dtw0 = dtw_g[(2 * 128 + d) * 4 + 0];
        const float dtw1 = dtw_g[(2 * 128 + d) * 4 + 1];
        const float dtw2 = dtw_g[(2 * 128 + d) * 4 + 2];
        const float dtw3 = dtw_g[(2 * 128 + d) * 4 + 3];
        const float dtb  = dtb_g[2 * 128 + d];
        const float Aneg = -__expf(alog[2 * 128 + d]);
        const float Dd   = ds_g[2 * 128 + d];
        float h = H0[((size_t)bk2 * NCH + c) * 128 + d];
#pragma unroll
        for (int i = 0; i < CS; ++i) {
            const float draw = fmaf(xd0_s[i*8+0], dtw0, fmaf(xd0_s[i*8+1], dtw1,
                               fmaf(xd0_s[i*8+2], dtw2, fmaf(xd0_s[i*8+3], dtw3, dtb))));
            const float dt  = softplus_(draw);
            const float dA  = __expf(dt * Aneg);
            h = fmaf(dA, h, dt * xd0_s[i*8+4] * xv[i]);
            y[i] = fmaf(h, xd0_s[i*8+5], Dd * xv[i]);
        }
    }
    // k = 3: step i -> window index (CS-1-i)
    {
        const float dtw0 = dtw_g[(3 * 128 + d) * 4 + 0];
        const float dtw1 = dtw_g[(3 * 128 + d) * 4 + 1];
        const float dtw2 = dtw_g[(3 * 128 + d) * 4 + 2];
        const float dtw3 = dtw_g[(3 * 128 + d) * 4 + 3];
        const float dtb  = dtb_g[3 * 128 + d];
        const float Aneg = -__expf(alog[3 * 128 + d]);
        const float Dd   = ds_g[3 * 128 + d];
        float h = H0[((size_t)bk3 * NCH + c2) * 128 + d];
#pragma unroll
        for (int i = 0; i < CS; ++i) {
            const int j = CS - 1 - i;
            const float draw = fmaf(xd1_s[i*8+0], dtw0, fmaf(xd1_s[i*8+1], dtw1,
                               fmaf(xd1_s[i*8+2], dtw2, fmaf(xd1_s[i*8+3], dtw3, dtb))));
            const float dt  = softplus_(draw);
            const float dA  = __expf(dt * Aneg);
            h = fmaf(dA, h, dt * xd1_s[i*8+4] * xv[j]);
            y[j] += fmaf(h, xd1_s[i*8+5], Dd * xv[j]);
        }
    }
#pragma unroll
    for (int i = 0; i < CS; ++i)
        atomicAdd(&yb[(size_t)pj[i] * 128 + d], y[i]);
}

// ---------------- Kernel E: LayerNorm + gate + spatial mean ----------------
__global__ __launch_bounds__(256) void k_final(const float* __restrict__ ysum,
                                               const float* __restrict__ zs,
                                               const float* __restrict__ onw,
                                               const float* __restrict__ onb,
                                               float* __restrict__ out)
{
    const int wid  = threadIdx.x >> 6;
    const int lane = threadIdx.x & 63;
    const int b     = blockIdx.x / 49;
    const int chunk = blockIdx.x % 49;
    const int pbase = chunk * 64 + wid * 16;

    const float w0 = onw[lane], w1 = onw[lane + 64];
    const float b0 = onb[lane], b1 = onb[lane + 64];

    float acc0 = 0.0f, acc1 = 0.0f;
    for (int i = 0; i < 16; ++i) {
        const int p = pbase + i;
        const float v0 = ysum[((size_t)b * LL + p) * 128 + lane];
        const float v1 = ysum[((size_t)b * LL + p) * 128 + lane + 64];
        float s = v0 + v1;
#pragma unroll
        for (int off = 32; off >= 1; off >>= 1) s += __shfl_xor(s, off, 64);
        const float mu = s * (1.0f / 128.0f);
        const float d0 = v0 - mu, d1 = v1 - mu;
        float sq = d0 * d0 + d1 * d1;
#pragma unroll
        for (int off = 32; off >= 1; off >>= 1) sq += __shfl_xor(sq, off, 64);
        const float rstd = rsqrtf(sq * (1.0f / 128.0f) + 1e-5f);
        const float yn0 = fmaf(d0 * rstd, w0, b0);
        const float yn1 = fmaf(d1 * rstd, w1, b1);
        const float g0 = zs[((size_t)b * LL + p) * 128 + lane];
        const float g1 = zs[((size_t)b * LL + p) * 128 + lane + 64];
        acc0 = fmaf(yn0, g0, acc0);
        acc1 = fmaf(yn1, g1, acc1);
    }
    atomicAdd(&out[b * 128 + lane],      acc0 * (1.0f / (float)LL));
    atomicAdd(&out[b * 128 + lane + 64], acc1 * (1.0f / (float)LL));
}

extern "C" void kernel_launch(void* const* d_in, const int* in_sizes, int n_in,
                              void* d_out, int out_size, void* d_ws, size_t ws_size,
                              hipStream_t stream)
{
    const float* x     = (const float*)d_in[0];
    const float* ipw   = (const float*)d_in[1];
    const float* cw    = (const float*)d_in[2];
    const float* cb    = (const float*)d_in[3];
    const float* xpw   = (const float*)d_in[4];
    const float* dtw   = (const float*)d_in[5];
    const float* dtb   = (const float*)d_in[6];
    const float* alog  = (const float*)d_in[7];
    const float* dsg   = (const float*)d_in[8];
    const float* onw   = (const float*)d_in[9];
    const float* onb   = (const float*)d_in[10];
    float* out = (float*)d_out;

    float* ws   = (float*)d_ws;
    float* xi   = ws + OFF_XI;     // becomes ysum after convproj
    float* zs   = ws + OFF_ZS;
    float* xc   = ws + OFF_XC;
    float* xdbl = ws + OFF_XDBL;
    float* Pa   = ws + OFF_PA;
    float* Hl   = ws + OFF_HL;
    float* H0   = ws + OFF_H0;
    float* ysum = xi;

    hipMemsetAsync(out, 0, (size_t)out_size * 4, stream);

    k_inproj<<<784, 256, 0, stream>>>(x, ipw, xi, zs);
    k_convproj<<<BB * 49, 256, 0, stream>>>(xi, cw, cb, xpw, xc, xdbl);

    k_scan1<<<BB * KK * NCH, 128, 0, stream>>>(xc, xdbl, dtw, dtb, alog, Pa, Hl);
    k_scan2<<<BB * KK, 128, 0, stream>>>(Pa, Hl, H0);
    k_scan3a<<<BB * NCH, 128, 0, stream>>>(xc, xdbl, dtw, dtb, alog, dsg, H0, ysum);
    k_scan3b<<<BB * NCH, 128, 0, stream>>>(xc, xdbl, dtw, dtb, alog, dsg, H0, ysum);

    k_final<<<BB * 49, 256, 0, stream>>>(ysum, zs, onw, onb, out);
}

// Round 4
// 338.850 us; speedup vs baseline: 5.4252x; 1.1255x over previous
//
#include <hip/hip_runtime.h>
#include <math.h>

#define BB   16
#define HHH  56
#define WWW  56
#define LL   3136      // 56*56
#define DI_  128
#define KK   4
#define NCH  98        // chunks per (b,k)
#define CS   32        // chunk size; NCH*CS == LL

// workspace layout (floats)
#define OFF_XI   ((size_t)0)           // B*L*DI ; reused as YSUM after conv
#define OFF_ZS   ((size_t)6422528)
#define OFF_XC   ((size_t)12845056)
#define OFF_XDN  ((size_t)19267584)    // B*L*32 = 1605632 (proj rows, natural order)
#define OFF_PA   ((size_t)20873216)    // B*K*NCH*128 = 802816
#define OFF_HL   ((size_t)21676032)
#define OFF_H0   ((size_t)22478848)

__device__ __forceinline__ float sigmoidf_(float x) { return 1.0f / (1.0f + __expf(-x)); }

// softplus, branchless, abs err ~1e-7
__device__ __forceinline__ float softplus_(float x) {
    return fmaxf(x, 0.0f) + __logf(1.0f + __expf(-fabsf(x)));
}

__device__ __forceinline__ int pmap(int k, int l) {
    if (k == 0) return l;
    if (k == 1) return LL - 1 - l;
    if (k == 2) return (l % HHH) * WWW + (l / HHH);
    const int l2 = LL - 1 - l;
    return (l2 % HHH) * WWW + (l2 / HHH);
}

// ---------------- Kernel A: in_proj GEMM + split + silu(z) ----------------
__global__ __launch_bounds__(256) void k_inproj(const float* __restrict__ x,
                                                const float* __restrict__ Wp,
                                                float* __restrict__ xi,
                                                float* __restrict__ zs)
{
    __shared__ float As[128 * 64];
    __shared__ float Ws[128 * 64];
    const int tid  = threadIdx.x;
    const int row0 = blockIdx.x * 64;
    const int r  = tid & 63;
    const int cg = tid >> 6;

#pragma unroll
    for (int i = 0; i < 8; ++i) {
        const int k0 = cg * 4 + i * 16;
        float4 v = *(const float4*)&x[(size_t)(row0 + r) * 128 + k0];
        As[(k0 + 0) * 64 + r] = v.x;
        As[(k0 + 1) * 64 + r] = v.y;
        As[(k0 + 2) * 64 + r] = v.z;
        As[(k0 + 3) * 64 + r] = v.w;
    }

    const int tx = tid & 15;
    const int ty = tid >> 4;

    for (int cb = 0; cb < 4; ++cb) {
        const int col0 = cb * 64;
        __syncthreads();
#pragma unroll
        for (int i = 0; i < 8; ++i) {
            const int k0 = cg * 4 + i * 16;
            float4 u = *(const float4*)&Wp[(size_t)(col0 + r) * 128 + k0];
            Ws[(k0 + 0) * 64 + r] = u.x;
            Ws[(k0 + 1) * 64 + r] = u.y;
            Ws[(k0 + 2) * 64 + r] = u.z;
            Ws[(k0 + 3) * 64 + r] = u.w;
        }
        __syncthreads();

        float acc[4][4];
#pragma unroll
        for (int i = 0; i < 4; ++i)
#pragma unroll
            for (int j = 0; j < 4; ++j) acc[i][j] = 0.0f;

#pragma unroll 4
        for (int kk = 0; kk < 128; ++kk) {
            float4 a4 = *(const float4*)&As[kk * 64 + ty * 4];
            float4 b4 = *(const float4*)&Ws[kk * 64 + tx * 4];
            const float a[4] = {a4.x, a4.y, a4.z, a4.w};
            const float b[4] = {b4.x, b4.y, b4.z, b4.w};
#pragma unroll
            for (int i = 0; i < 4; ++i)
#pragma unroll
                for (int j = 0; j < 4; ++j) acc[i][j] = fmaf(a[i], b[j], acc[i][j]);
        }

#pragma unroll
        for (int i = 0; i < 4; ++i) {
            const size_t row = row0 + ty * 4 + i;
#pragma unroll
            for (int j = 0; j < 4; ++j) {
                const int col = col0 + tx * 4 + j;
                const float v = acc[i][j];
                if (col < 128) {
                    xi[row * 128 + col] = v;
                } else {
                    zs[row * 128 + (col - 128)] = v * sigmoidf_(v);
                }
            }
        }
    }
}

// ---------------- Kernel B: depthwise 3x3 conv + bias + silu (streaming) ----------------
__global__ __launch_bounds__(256) void k_conv(const float* __restrict__ xi,
                                              const float* __restrict__ cw,
                                              const float* __restrict__ cb,
                                              float* __restrict__ xc)
{
    const size_t idx = (size_t)blockIdx.x * 256 + threadIdx.x;
    if (idx >= (size_t)BB * LL * DI_) return;
    const int d    = idx & 127;
    const int rest = (int)(idx >> 7);
    const int p    = rest % LL;
    const int b    = rest / LL;
    const int h    = p / WWW;
    const int w    = p % WWW;

    float acc = cb[d];
#pragma unroll
    for (int dh = -1; dh <= 1; ++dh) {
        const int hh = h + dh;
        if (hh < 0 || hh >= HHH) continue;
#pragma unroll
        for (int dw = -1; dw <= 1; ++dw) {
            const int ww = w + dw;
            if (ww < 0 || ww >= WWW) continue;
            const float xv = xi[((size_t)b * LL + hh * WWW + ww) * 128 + d];
            acc = fmaf(xv, cw[d * 9 + (dh + 1) * 3 + (dw + 1)], acc);
        }
    }
    xc[idx] = acc * sigmoidf_(acc);
}

// ---------------- Kernel C: projection in natural order ----------------
// Y[b][p][k*8+c] = sum_d xc[b,p,d] * W[k,c,d]  -- permutation applied at READ time in scans
__global__ __launch_bounds__(256) void k_projN(const float* __restrict__ xc,
                                               const float* __restrict__ xpw,
                                               float* __restrict__ xdn)
{
    __shared__ float xs[64 * 129];
    __shared__ float wl[24 * 128];
    const int tid = threadIdx.x;
    const int b   = blockIdx.x / 49;
    const int p0  = (blockIdx.x % 49) * 64;

    for (int i = tid; i < 24 * 128; i += 256) wl[i] = xpw[i];

    // stage xc tile 64x128 (coalesced float4)
#pragma unroll
    for (int i = 0; i < 8; ++i) {
        const int idx4 = i * 256 + tid;
        const int row  = idx4 >> 5;
        const int d4   = (idx4 & 31) * 4;
        float4 v = *(const float4*)&xc[((size_t)b * LL + p0 + row) * 128 + d4];
        xs[row * 129 + d4 + 0] = v.x;
        xs[row * 129 + d4 + 1] = v.y;
        xs[row * 129 + d4 + 2] = v.z;
        xs[row * 129 + d4 + 3] = v.w;
    }
    __syncthreads();

    const int ks   = tid >> 6;     // wave = direction
    const int lane = tid & 63;     // lane = position
    float a0 = 0.f, a1 = 0.f, a2 = 0.f, a3 = 0.f, a4 = 0.f, a5 = 0.f;
    const float* wb = &wl[ks * 6 * 128];
#pragma unroll 4
    for (int d = 0; d < 128; ++d) {
        const float xv = xs[lane * 129 + d];
        a0 = fmaf(xv, wb[0 * 128 + d], a0);
        a1 = fmaf(xv, wb[1 * 128 + d], a1);
        a2 = fmaf(xv, wb[2 * 128 + d], a2);
        a3 = fmaf(xv, wb[3 * 128 + d], a3);
        a4 = fmaf(xv, wb[4 * 128 + d], a4);
        a5 = fmaf(xv, wb[5 * 128 + d], a5);
    }
    float* o = &xdn[((size_t)(b * LL + p0 + lane)) * 32 + ks * 8];
    o[0] = a0; o[1] = a1; o[2] = a2; o[3] = a3; o[4] = a4; o[5] = a5;
}

// ---------------- Scan pass 1: per-chunk summaries ----------------
__global__ __launch_bounds__(128) void k_scan1(const float* __restrict__ xc,
                                               const float* __restrict__ xdn,
                                               const float* __restrict__ dtw_g,
                                               const float* __restrict__ dtb_g,
                                               const float* __restrict__ alog,
                                               float* __restrict__ Pa,
                                               float* __restrict__ Hl)
{
    const int bk = blockIdx.x / NCH;
    const int c  = blockIdx.x % NCH;
    const int b  = bk >> 2;
    const int k  = bk & 3;
    const int d  = threadIdx.x;
    const int l0 = c * CS;

    const float dtw0 = dtw_g[(k * 128 + d) * 4 + 0];
    const float dtw1 = dtw_g[(k * 128 + d) * 4 + 1];
    const float dtw2 = dtw_g[(k * 128 + d) * 4 + 2];
    const float dtw3 = dtw_g[(k * 128 + d) * 4 + 3];
    const float dtb  = dtb_g[k * 128 + d];
    const float Aneg = -__expf(alog[k * 128 + d]);
    const float* xcb = &xc[(size_t)b * LL * 128];
    const float* xb  = &xdn[(size_t)b * LL * 32 + k * 8];

    float P = 1.0f, h = 0.0f;
#pragma unroll 4
    for (int i = 0; i < CS; ++i) {
        const int p = pmap(k, l0 + i);
        const float* row = &xb[(size_t)p * 32];   // wave-uniform -> scalar loads
        const float xv  = xcb[(size_t)p * 128 + d];
        const float draw = fmaf(row[0], dtw0, fmaf(row[1], dtw1,
                           fmaf(row[2], dtw2, fmaf(row[3], dtw3, dtb))));
        const float dt  = softplus_(draw);
        const float dA  = __expf(dt * Aneg);
        P *= dA;
        h = fmaf(dA, h, dt * row[4] * xv);
    }
    Pa[(size_t)blockIdx.x * 128 + d] = P;
    Hl[(size_t)blockIdx.x * 128 + d] = h;
}

// ---------------- Scan pass 2: combine chunk summaries ----------------
__global__ __launch_bounds__(128) void k_scan2(const float* __restrict__ Pa,
                                               const float* __restrict__ Hl,
                                               float* __restrict__ H0)
{
    const int bk = blockIdx.x;
    const int d  = threadIdx.x;
    float h = 0.0f;
    for (int c = 0; c < NCH; ++c) {
        const size_t o = ((size_t)bk * NCH + c) * 128 + d;
        H0[o] = h;
        h = fmaf(Pa[o], h, Hl[o]);
    }
}

// ---------------- Scan pass 3a: directions 0+1 paired, plain store ----------------
__global__ __launch_bounds__(128) void k_scan3a(const float* __restrict__ xc,
                                                const float* __restrict__ xdn,
                                                const float* __restrict__ dtw_g,
                                                const float* __restrict__ dtb_g,
                                                const float* __restrict__ alog,
                                                const float* __restrict__ ds_g,
                                                const float* __restrict__ H0,
                                                float* __restrict__ ysum)
{
    const int b = blockIdx.x / NCH;
    const int c = blockIdx.x % NCH;
    const int d = threadIdx.x;
    const int c2 = NCH - 1 - c;
    const int bk0 = b * 4 + 0, bk1 = b * 4 + 1;
    const int l0a = c * CS;

    const float* xcb  = &xc[(size_t)b * LL * 128];
    const float* base = &xdn[(size_t)b * LL * 32];
    float* yb = &ysum[(size_t)b * LL * 128];

    float xv[CS];
#pragma unroll
    for (int i = 0; i < CS; ++i) xv[i] = xcb[(size_t)(l0a + i) * 128 + d];

    float y[CS];

    // k = 0: step i at p = l0a + i, row offset 0
    {
        const float dtw0 = dtw_g[(0 * 128 + d) * 4 + 0];
        const float dtw1 = dtw_g[(0 * 128 + d) * 4 + 1];
        const float dtw2 = dtw_g[(0 * 128 + d) * 4 + 2];
        const float dtw3 = dtw_g[(0 * 128 + d) * 4 + 3];
        const float dtb  = dtb_g[0 * 128 + d];
        const float Aneg = -__expf(alog[0 * 128 + d]);
        const float Dd   = ds_g[0 * 128 + d];
        float h = H0[((size_t)bk0 * NCH + c) * 128 + d];
#pragma unroll
        for (int i = 0; i < CS; ++i) {
            const float* row = &base[(size_t)(l0a + i) * 32];
            const float draw = fmaf(row[0], dtw0, fmaf(row[1], dtw1,
                               fmaf(row[2], dtw2, fmaf(row[3], dtw3, dtb))));
            const float dt  = softplus_(draw);
            const float dA  = __expf(dt * Aneg);
            h = fmaf(dA, h, dt * row[4] * xv[i]);
            y[i] = fmaf(h, row[5], Dd * xv[i]);
        }
    }
    // k = 1: step i at p = l0a + (CS-1-i), row offset 8
    {
        const float dtw0 = dtw_g[(1 * 128 + d) * 4 + 0];
        const float dtw1 = dtw_g[(1 * 128 + d) * 4 + 1];
        const float dtw2 = dtw_g[(1 * 128 + d) * 4 + 2];
        const float dtw3 = dtw_g[(1 * 128 + d) * 4 + 3];
        const float dtb  = dtb_g[1 * 128 + d];
        const float Aneg = -__expf(alog[1 * 128 + d]);
        const float Dd   = ds_g[1 * 128 + d];
        float h = H0[((size_t)bk1 * NCH + c2) * 128 + d];
#pragma unroll
        for (int i = 0; i < CS; ++i) {
            const int j = CS - 1 - i;
            const float* row = &base[(size_t)(l0a + j) * 32 + 8];
            const float draw = fmaf(row[0], dtw0, fmaf(row[1], dtw1,
                               fmaf(row[2], dtw2, fmaf(row[3], dtw3, dtb))));
            const float dt  = softplus_(draw);
            const float dA  = __expf(dt * Aneg);
            h = fmaf(dA, h, dt * row[4] * xv[j]);
            y[j] += fmaf(h, row[5], Dd * xv[j]);
        }
    }
#pragma unroll
    for (int i = 0; i < CS; ++i)
        yb[(size_t)(l0a + i) * 128 + d] = y[i];
}

// ---------------- Scan pass 3b: directions 2+3 paired, atomic add ----------------
__global__ __launch_bounds__(128) void k_scan3b(const float* __restrict__ xc,
                                                const float* __restrict__ xdn,
                                                const float* __restrict__ dtw_g,
                                                const float* __restrict__ dtb_g,
                                                const float* __restrict__ alog,
                                                const float* __restrict__ ds_g,
                                                const float* __restrict__ H0,
                                                float* __restrict__ ysum)
{
    const int b = blockIdx.x / NCH;
    const int c = blockIdx.x % NCH;
    const int d = threadIdx.x;
    const int c2 = NCH - 1 - c;
    const int bk2 = b * 4 + 2, bk3 = b * 4 + 3;
    const int l0a = c * CS;

    const float* xcb  = &xc[(size_t)b * LL * 128];
    const float* base = &xdn[(size_t)b * LL * 32];
    float* yb = &ysum[(size_t)b * LL * 128];

    int pj[CS];
#pragma unroll
    for (int i = 0; i < CS; ++i) {
        const int l = l0a + i;
        pj[i] = (l % HHH) * WWW + (l / HHH);
    }
    float xv[CS];
#pragma unroll
    for (int i = 0; i < CS; ++i) xv[i] = xcb[(size_t)pj[i] * 128 + d];

    float y[CS];

    // k = 2: step i at p = pj[i], row offset 16
    {
        const float dtw0 = dtw_g[(2 * 128 + d) * 4 + 0];
        const float dtw1 = dtw_g[(2 * 128 + d) * 4 + 1];
        const float dtw2 = dtw_g[(2 * 128 + d) * 4 + 2];
        const float dtw3 = dtw_g[(2 * 128 + d) * 4 + 3];
        const float dtb  = dtb_g[2 * 128 + d];
        const float Aneg = -__expf(alog[2 * 128 + d]);
        const float Dd   = ds_g[2 * 128 + d];
        float h = H0[((size_t)bk2 * NCH + c) * 128 + d];
#pragma unroll
        for (int i = 0; i < CS; ++i) {
            const float* row = &base[(size_t)pj[i] * 32 + 16];
            const float draw = fmaf(row[0], dtw0, fmaf(row[1], dtw1,
                               fmaf(row[2], dtw2, fmaf(row[3], dtw3, dtb))));
            const float dt  = softplus_(draw);
            const float dA  = __expf(dt * Aneg);
            h = fmaf(dA, h, dt * row[4] * xv[i]);
            y[i] = fmaf(h, row[5], Dd * xv[i]);
        }
    }
    // k = 3: step i at p = pj[CS-1-i], row offset 24
    {
        const float dtw0 = dtw_g[(3 * 128 + d) * 4 + 0];
        const float dtw1 = dtw_g[(3 * 128 + d) * 4 + 1];
        const float dtw2 = dtw_g[(3 * 128 + d) * 4 + 2];
        const float dtw3 = dtw_g[(3 * 128 + d) * 4 + 3];
        const float dtb  = dtb_g[3 * 128 + d];
        const float Aneg = -__expf(alog[3 * 128 + d]);
        const float Dd   = ds_g[3 * 128 + d];
        float h = H0[((size_t)bk3 * NCH + c2) * 128 + d];
#pragma unroll
        for (int i = 0; i < CS; ++i) {
            const int j = CS - 1 - i;
            const float* row = &base[(size_t)pj[j] * 32 + 24];
            const float draw = fmaf(row[0], dtw0, fmaf(row[1], dtw1,
                               fmaf(row[2], dtw2, fmaf(row[3], dtw3, dtb))));
            const float dt  = softplus_(draw);
            const float dA  = __expf(dt * Aneg);
            h = fmaf(dA, h, dt * row[4] * xv[j]);
            y[j] += fmaf(h, row[5], Dd * xv[j]);
        }
    }
#pragma unroll
    for (int i = 0; i < CS; ++i)
        atomicAdd(&yb[(size_t)pj[i] * 128 + d], y[i]);
}

// ---------------- Kernel E: LayerNorm + gate + spatial mean ----------------
__global__ __launch_bounds__(256) void k_final(const float* __restrict__ ysum,
                                               const float* __restrict__ zs,
                                               const float* __restrict__ onw,
                                               const float* __restrict__ onb,
                                               float* __restrict__ out)
{
    const int wid  = threadIdx.x >> 6;
    const int lane = threadIdx.x & 63;
    const int b     = blockIdx.x / 49;
    const int chunk = blockIdx.x % 49;
    const int pbase = chunk * 64 + wid * 16;

    const float w0 = onw[lane], w1 = onw[lane + 64];
    const float b0 = onb[lane], b1 = onb[lane + 64];

    float acc0 = 0.0f, acc1 = 0.0f;
    for (int i = 0; i < 16; ++i) {
        const int p = pbase + i;
        const float v0 = ysum[((size_t)b * LL + p) * 128 + lane];
        const float v1 = ysum[((size_t)b * LL + p) * 128 + lane + 64];
        float s = v0 + v1;
#pragma unroll
        for (int off = 32; off >= 1; off >>= 1) s += __shfl_xor(s, off, 64);
        const float mu = s * (1.0f / 128.0f);
        const float d0 = v0 - mu, d1 = v1 - mu;
        float sq = d0 * d0 + d1 * d1;
#pragma unroll
        for (int off = 32; off >= 1; off >>= 1) sq += __shfl_xor(sq, off, 64);
        const float rstd = rsqrtf(sq * (1.0f / 128.0f) + 1e-5f);
        const float yn0 = fmaf(d0 * rstd, w0, b0);
        const float yn1 = fmaf(d1 * rstd, w1, b1);
        const float g0 = zs[((size_t)b * LL + p) * 128 + lane];
        const float g1 = zs[((size_t)b * LL + p) * 128 + lane + 64];
        acc0 = fmaf(yn0, g0, acc0);
        acc1 = fmaf(yn1, g1, acc1);
    }
    atomicAdd(&out[b * 128 + lane],      acc0 * (1.0f / (float)LL));
    atomicAdd(&out[b * 128 + lane + 64], acc1 * (1.0f / (float)LL));
}

extern "C" void kernel_launch(void* const* d_in, const int* in_sizes, int n_in,
                              void* d_out, int out_size, void* d_ws, size_t ws_size,
                              hipStream_t stream)
{
    const float* x     = (const float*)d_in[0];
    const float* ipw   = (const float*)d_in[1];
    const float* cw    = (const float*)d_in[2];
    const float* cb    = (const float*)d_in[3];
    const float* xpw   = (const float*)d_in[4];
    const float* dtw   = (const float*)d_in[5];
    const float* dtb   = (const float*)d_in[6];
    const float* alog  = (const float*)d_in[7];
    const float* dsg   = (const float*)d_in[8];
    const float* onw   = (const float*)d_in[9];
    const float* onb   = (const float*)d_in[10];
    float* out = (float*)d_out;

    float* ws   = (float*)d_ws;
    float* xi   = ws + OFF_XI;     // becomes ysum after conv
    float* zs   = ws + OFF_ZS;
    float* xc   = ws + OFF_XC;
    float* xdn  = ws + OFF_XDN;
    float* Pa   = ws + OFF_PA;
    float* Hl   = ws + OFF_HL;
    float* H0   = ws + OFF_H0;
    float* ysum = xi;

    hipMemsetAsync(out, 0, (size_t)out_size * 4, stream);

    k_inproj<<<784, 256, 0, stream>>>(x, ipw, xi, zs);

    const size_t totB = (size_t)BB * LL * DI_;
    k_conv<<<(int)((totB + 255) / 256), 256, 0, stream>>>(xi, cw, cb, xc);

    k_projN<<<BB * 49, 256, 0, stream>>>(xc, xpw, xdn);

    k_scan1<<<BB * KK * NCH, 128, 0, stream>>>(xc, xdn, dtw, dtb, alog, Pa, Hl);
    k_scan2<<<BB * KK, 128, 0, stream>>>(Pa, Hl, H0);
    k_scan3a<<<BB * NCH, 128, 0, stream>>>(xc, xdn, dtw, dtb, alog, dsg, H0, ysum);
    k_scan3b<<<BB * NCH, 128, 0, stream>>>(xc, xdn, dtw, dtb, alog, dsg, H0, ysum);

    k_final<<<BB * 49, 256, 0, stream>>>(ysum, zs, onw, onb, out);
}

// Round 5
// 309.721 us; speedup vs baseline: 5.9354x; 1.0941x over previous
//
#include <hip/hip_runtime.h>
#include <math.h>

#define BB   16
#define HHH  56
#define WWW  56
#define LL   3136      // 56*56
#define DI_  128
#define KK   4
#define NCH  98        // chunks per (b,k)
#define CS   32        // chunk size; NCH*CS == LL

// workspace layout (floats)
#define OFF_XI   ((size_t)0)           // B*L*DI ; reused as YSUM
#define OFF_ZS   ((size_t)6422528)
#define OFF_XC   ((size_t)12845056)    // xc; also hosts Whi/Wlo BEFORE k_conv writes it
#define OFF_XDN  ((size_t)19267584)    // B*L*32
#define OFF_PA   ((size_t)20873216)
#define OFF_HL   ((size_t)21676032)
#define OFF_H0   ((size_t)22478848)

typedef short s16x8 __attribute__((ext_vector_type(8)));
typedef float f32x4 __attribute__((ext_vector_type(4)));

__device__ __forceinline__ float sigmoidf_(float x) { return 1.0f / (1.0f + __expf(-x)); }
__device__ __forceinline__ float softplus_(float x) {
    return fmaxf(x, 0.0f) + __logf(1.0f + __expf(-fabsf(x)));
}
__device__ __forceinline__ int pmap(int k, int l) {
    if (k == 0) return l;
    if (k == 1) return LL - 1 - l;
    if (k == 2) return (l % HHH) * WWW + (l / HHH);
    const int l2 = LL - 1 - l;
    return (l2 % HHH) * WWW + (l2 / HHH);
}

// split f into bf16 hi/lo (RNE)
__device__ __forceinline__ void bf16split(float f, short* hi, short* lo) {
    unsigned u = __float_as_uint(f);
    unsigned r = u + 0x7FFFu + ((u >> 16) & 1u);
    *hi = (short)(r >> 16);
    float hf = __uint_as_float(r & 0xFFFF0000u);
    float l  = f - hf;
    unsigned u2 = __float_as_uint(l);
    unsigned r2 = u2 + 0x7FFFu + ((u2 >> 16) & 1u);
    *lo = (short)(r2 >> 16);
}

// ---------------- Kernel W: pre-split in_proj weights to bf16 hi/lo ----------------
__global__ __launch_bounds__(256) void k_wsplit(const float* __restrict__ Wp,
                                                short* __restrict__ Whi,
                                                short* __restrict__ Wlo)
{
    const int idx = blockIdx.x * 256 + threadIdx.x;
    if (idx >= 256 * 128) return;
    short h, l;
    bf16split(Wp[idx], &h, &l);
    Whi[idx] = h;
    Wlo[idx] = l;
}

// ---------------- Kernel A: in_proj GEMM via bf16x3 MFMA ----------------
// grid: 784 blocks (64-row tiles); 256 thr = 4 waves; wave w -> 16-col strip per 64-col group
#define APAD 136   // 128 + 8 shorts row pad (272B stride)
__global__ __launch_bounds__(256) void k_inproj(const float* __restrict__ x,
                                                const short* __restrict__ Whi,
                                                const short* __restrict__ Wlo,
                                                float* __restrict__ xi,
                                                float* __restrict__ zs)
{
    __shared__ short Ahi[64 * APAD];
    __shared__ short Alo[64 * APAD];
    const int tid  = threadIdx.x;
    const int row0 = blockIdx.x * 64;

    // stage + split A tile (64 rows x 128 k)
#pragma unroll
    for (int i = 0; i < 8; ++i) {
        const int idx4 = i * 256 + tid;
        const int row  = idx4 >> 5;
        const int k4   = (idx4 & 31) * 4;
        float4 v = *(const float4*)&x[(size_t)(row0 + row) * 128 + k4];
        const float f[4] = {v.x, v.y, v.z, v.w};
#pragma unroll
        for (int j = 0; j < 4; ++j) {
            short h, l;
            bf16split(f[j], &h, &l);
            Ahi[row * APAD + k4 + j] = h;
            Alo[row * APAD + k4 + j] = l;
        }
    }
    __syncthreads();

    const int w    = tid >> 6;
    const int lane = tid & 63;
    const int lr   = lane & 15;       // row-in-tile / col-in-tile
    const int lk   = (lane >> 4) * 8; // k sub-offset

    for (int cg = 0; cg < 4; ++cg) {
        const int col0 = cg * 64 + w * 16;
        // hoist B fragments (hi/lo x 4 K-steps)
        s16x8 bhi[4], blo[4];
#pragma unroll
        for (int ks = 0; ks < 4; ++ks) {
            const size_t wo = (size_t)(col0 + lr) * 128 + ks * 32 + lk;
            bhi[ks] = *(const s16x8*)&Whi[wo];
            blo[ks] = *(const s16x8*)&Wlo[wo];
        }
#pragma unroll
        for (int rt = 0; rt < 4; ++rt) {
            f32x4 acc = {0.f, 0.f, 0.f, 0.f};
#pragma unroll
            for (int ks = 0; ks < 4; ++ks) {
                const int ao = (rt * 16 + lr) * APAD + ks * 32 + lk;
                s16x8 ahi = *(const s16x8*)&Ahi[ao];
                s16x8 alo = *(const s16x8*)&Alo[ao];
                acc = __builtin_amdgcn_mfma_f32_16x16x32_bf16(alo, bhi[ks], acc, 0, 0, 0);
                acc = __builtin_amdgcn_mfma_f32_16x16x32_bf16(ahi, blo[ks], acc, 0, 0, 0);
                acc = __builtin_amdgcn_mfma_f32_16x16x32_bf16(ahi, bhi[ks], acc, 0, 0, 0);
            }
            const int col = col0 + lr;
#pragma unroll
            for (int j = 0; j < 4; ++j) {
                const size_t row = row0 + rt * 16 + (lane >> 4) * 4 + j;
                const float v = acc[j];
                if (col < 128) {
                    xi[row * 128 + col] = v;
                } else {
                    zs[row * 128 + (col - 128)] = v * sigmoidf_(v);
                }
            }
        }
    }
}

// ---------------- Kernel B: depthwise 3x3 conv + bias + silu (streaming) ----------------
__global__ __launch_bounds__(256) void k_conv(const float* __restrict__ xi,
                                              const float* __restrict__ cw,
                                              const float* __restrict__ cb,
                                              float* __restrict__ xc)
{
    const size_t idx = (size_t)blockIdx.x * 256 + threadIdx.x;
    if (idx >= (size_t)BB * LL * DI_) return;
    const int d    = idx & 127;
    const int rest = (int)(idx >> 7);
    const int p    = rest % LL;
    const int b    = rest / LL;
    const int h    = p / WWW;
    const int w    = p % WWW;

    float acc = cb[d];
#pragma unroll
    for (int dh = -1; dh <= 1; ++dh) {
        const int hh = h + dh;
        if (hh < 0 || hh >= HHH) continue;
#pragma unroll
        for (int dw = -1; dw <= 1; ++dw) {
            const int ww = w + dw;
            if (ww < 0 || ww >= WWW) continue;
            const float xv = xi[((size_t)b * LL + hh * WWW + ww) * 128 + d];
            acc = fmaf(xv, cw[d * 9 + (dh + 1) * 3 + (dw + 1)], acc);
        }
    }
    xc[idx] = acc * sigmoidf_(acc);
}

// ---------------- Kernel C: projection in natural order ----------------
__global__ __launch_bounds__(256) void k_projN(const float* __restrict__ xc,
                                               const float* __restrict__ xpw,
                                               float* __restrict__ xdn)
{
    __shared__ float xs[64 * 129];
    __shared__ float wl[24 * 128];
    const int tid = threadIdx.x;
    const int b   = blockIdx.x / 49;
    const int p0  = (blockIdx.x % 49) * 64;

    for (int i = tid; i < 24 * 128; i += 256) wl[i] = xpw[i];

#pragma unroll
    for (int i = 0; i < 8; ++i) {
        const int idx4 = i * 256 + tid;
        const int row  = idx4 >> 5;
        const int d4   = (idx4 & 31) * 4;
        float4 v = *(const float4*)&xc[((size_t)b * LL + p0 + row) * 128 + d4];
        xs[row * 129 + d4 + 0] = v.x;
        xs[row * 129 + d4 + 1] = v.y;
        xs[row * 129 + d4 + 2] = v.z;
        xs[row * 129 + d4 + 3] = v.w;
    }
    __syncthreads();

    const int ks   = tid >> 6;
    const int lane = tid & 63;
    float a0 = 0.f, a1 = 0.f, a2 = 0.f, a3 = 0.f, a4 = 0.f, a5 = 0.f;
    const float* wb = &wl[ks * 6 * 128];
#pragma unroll 4
    for (int d = 0; d < 128; ++d) {
        const float xv = xs[lane * 129 + d];
        a0 = fmaf(xv, wb[0 * 128 + d], a0);
        a1 = fmaf(xv, wb[1 * 128 + d], a1);
        a2 = fmaf(xv, wb[2 * 128 + d], a2);
        a3 = fmaf(xv, wb[3 * 128 + d], a3);
        a4 = fmaf(xv, wb[4 * 128 + d], a4);
        a5 = fmaf(xv, wb[5 * 128 + d], a5);
    }
    float* o = &xdn[((size_t)(b * LL + p0 + lane)) * 32 + ks * 8];
    o[0] = a0; o[1] = a1; o[2] = a2; o[3] = a3; o[4] = a4; o[5] = a5;
}

// ---------------- Scan pass 1 (merged direction pairs) ----------------
// grid: 2*BB*NCH; mode 0 -> dirs {0,1}, mode 1 -> dirs {2,3}
__global__ __launch_bounds__(128) void k_scan1m(const float* __restrict__ xc,
                                                const float* __restrict__ xdn,
                                                const float* __restrict__ dtw_g,
                                                const float* __restrict__ dtb_g,
                                                const float* __restrict__ alog,
                                                float* __restrict__ Pa,
                                                float* __restrict__ Hl)
{
    const int mode = blockIdx.x / (BB * NCH);
    const int rem  = blockIdx.x % (BB * NCH);
    const int b = rem / NCH;
    const int c = rem % NCH;
    const int d = threadIdx.x;
    const int c2 = NCH - 1 - c;
    const int l0a = c * CS;
    const int kA = mode * 2;       // 0 or 2
    const int kB = kA + 1;         // 1 or 3
    const int bkA = b * 4 + kA, bkB = b * 4 + kB;

    const float* xcb  = &xc[(size_t)b * LL * 128];
    const float* base = &xdn[(size_t)b * LL * 32];

    int pj[CS];
    if (mode == 0) {
#pragma unroll
        for (int i = 0; i < CS; ++i) pj[i] = l0a + i;
    } else {
#pragma unroll
        for (int i = 0; i < CS; ++i) {
            const int l = l0a + i;
            pj[i] = (l % HHH) * WWW + (l / HHH);
        }
    }
    float xv[CS];
#pragma unroll
    for (int i = 0; i < CS; ++i) xv[i] = xcb[(size_t)pj[i] * 128 + d];

    // dir kA: forward over window
    {
        const float dtw0 = dtw_g[(kA * 128 + d) * 4 + 0];
        const float dtw1 = dtw_g[(kA * 128 + d) * 4 + 1];
        const float dtw2 = dtw_g[(kA * 128 + d) * 4 + 2];
        const float dtw3 = dtw_g[(kA * 128 + d) * 4 + 3];
        const float dtb  = dtb_g[kA * 128 + d];
        const float Aneg = -__expf(alog[kA * 128 + d]);
        float P = 1.0f, h = 0.0f;
#pragma unroll
        for (int i = 0; i < CS; ++i) {
            const float* row = &base[(size_t)pj[i] * 32 + kA * 8];
            const float draw = fmaf(row[0], dtw0, fmaf(row[1], dtw1,
                               fmaf(row[2], dtw2, fmaf(row[3], dtw3, dtb))));
            const float dt  = softplus_(draw);
            const float dA  = __expf(dt * Aneg);
            P *= dA;
            h = fmaf(dA, h, dt * row[4] * xv[i]);
        }
        Pa[((size_t)bkA * NCH + c) * 128 + d] = P;
        Hl[((size_t)bkA * NCH + c) * 128 + d] = h;
    }
    // dir kB: chunk c2, reversed over the same window
    {
        const float dtw0 = dtw_g[(kB * 128 + d) * 4 + 0];
        const float dtw1 = dtw_g[(kB * 128 + d) * 4 + 1];
        const float dtw2 = dtw_g[(kB * 128 + d) * 4 + 2];
        const float dtw3 = dtw_g[(kB * 128 + d) * 4 + 3];
        const float dtb  = dtb_g[kB * 128 + d];
        const float Aneg = -__expf(alog[kB * 128 + d]);
        float P = 1.0f, h = 0.0f;
#pragma unroll
        for (int i = 0; i < CS; ++i) {
            const int j = CS - 1 - i;
            const float* row = &base[(size_t)pj[j] * 32 + kB * 8];
            const float draw = fmaf(row[0], dtw0, fmaf(row[1], dtw1,
                               fmaf(row[2], dtw2, fmaf(row[3], dtw3, dtb))));
            const float dt  = softplus_(draw);
            const float dA  = __expf(dt * Aneg);
            P *= dA;
            h = fmaf(dA, h, dt * row[4] * xv[j]);
        }
        Pa[((size_t)bkB * NCH + c2) * 128 + d] = P;
        Hl[((size_t)bkB * NCH + c2) * 128 + d] = h;
    }
}

// ---------------- Scan pass 2: combine chunk summaries ----------------
__global__ __launch_bounds__(128) void k_scan2(const float* __restrict__ Pa,
                                               const float* __restrict__ Hl,
                                               float* __restrict__ H0)
{
    const int bk = blockIdx.x;
    const int d  = threadIdx.x;
    float h = 0.0f;
#pragma unroll 7
    for (int c = 0; c < NCH; ++c) {
        const size_t o = ((size_t)bk * NCH + c) * 128 + d;
        H0[o] = h;
        h = fmaf(Pa[o], h, Hl[o]);
    }
}

// ---------------- Scan pass 3a: directions 0+1 paired, plain store ----------------
__global__ __launch_bounds__(128) void k_scan3a(const float* __restrict__ xc,
                                                const float* __restrict__ xdn,
                                                const float* __restrict__ dtw_g,
                                                const float* __restrict__ dtb_g,
                                                const float* __restrict__ alog,
                                                const float* __restrict__ ds_g,
                                                const float* __restrict__ H0,
                                                float* __restrict__ ysum)
{
    const int b = blockIdx.x / NCH;
    const int c = blockIdx.x % NCH;
    const int d = threadIdx.x;
    const int c2 = NCH - 1 - c;
    const int bk0 = b * 4 + 0, bk1 = b * 4 + 1;
    const int l0a = c * CS;

    const float* xcb  = &xc[(size_t)b * LL * 128];
    const float* base = &xdn[(size_t)b * LL * 32];
    float* yb = &ysum[(size_t)b * LL * 128];

    float xv[CS];
#pragma unroll
    for (int i = 0; i < CS; ++i) xv[i] = xcb[(size_t)(l0a + i) * 128 + d];

    float y[CS];

    {
        const float dtw0 = dtw_g[(0 * 128 + d) * 4 + 0];
        const float dtw1 = dtw_g[(0 * 128 + d) * 4 + 1];
        const float dtw2 = dtw_g[(0 * 128 + d) * 4 + 2];
        const float dtw3 = dtw_g[(0 * 128 + d) * 4 + 3];
        const float dtb  = dtb_g[0 * 128 + d];
        const float Aneg = -__expf(alog[0 * 128 + d]);
        const float Dd   = ds_g[0 * 128 + d];
        float h = H0[((size_t)bk0 * NCH + c) * 128 + d];
#pragma unroll
        for (int i = 0; i < CS; ++i) {
            const float* row = &base[(size_t)(l0a + i) * 32];
            const float draw = fmaf(row[0], dtw0, fmaf(row[1], dtw1,
                               fmaf(row[2], dtw2, fmaf(row[3], dtw3, dtb))));
            const float dt  = softplus_(draw);
            const float dA  = __expf(dt * Aneg);
            h = fmaf(dA, h, dt * row[4] * xv[i]);
            y[i] = fmaf(h, row[5], Dd * xv[i]);
        }
    }
    {
        const float dtw0 = dtw_g[(1 * 128 + d) * 4 + 0];
        const float dtw1 = dtw_g[(1 * 128 + d) * 4 + 1];
        const float dtw2 = dtw_g[(1 * 128 + d) * 4 + 2];
        const float dtw3 = dtw_g[(1 * 128 + d) * 4 + 3];
        const float dtb  = dtb_g[1 * 128 + d];
        const float Aneg = -__expf(alog[1 * 128 + d]);
        const float Dd   = ds_g[1 * 128 + d];
        float h = H0[((size_t)bk1 * NCH + c2) * 128 + d];
#pragma unroll
        for (int i = 0; i < CS; ++i) {
            const int j = CS - 1 - i;
            const float* row = &base[(size_t)(l0a + j) * 32 + 8];
            const float draw = fmaf(row[0], dtw0, fmaf(row[1], dtw1,
                               fmaf(row[2], dtw2, fmaf(row[3], dtw3, dtb))));
            const float dt  = softplus_(draw);
            const float dA  = __expf(dt * Aneg);
            h = fmaf(dA, h, dt * row[4] * xv[j]);
            y[j] += fmaf(h, row[5], Dd * xv[j]);
        }
    }
#pragma unroll
    for (int i = 0; i < CS; ++i)
        yb[(size_t)(l0a + i) * 128 + d] = y[i];
}

// ---------------- Scan pass 3b: directions 2+3 paired, atomic add ----------------
__global__ __launch_bounds__(128) void k_scan3b(const float* __restrict__ xc,
                                                const float* __restrict__ xdn,
                                                const float* __restrict__ dtw_g,
                                                const float* __restrict__ dtb_g,
                                                const float* __restrict__ alog,
                                                const float* __restrict__ ds_g,
                                                const float* __restrict__ H0,
                                                float* __restrict__ ysum)
{
    const int b = blockIdx.x / NCH;
    const int c = blockIdx.x % NCH;
    const int d = threadIdx.x;
    const int c2 = NCH - 1 - c;
    const int bk2 = b * 4 + 2, bk3 = b * 4 + 3;
    const int l0a = c * CS;

    const float* xcb  = &xc[(size_t)b * LL * 128];
    const float* base = &xdn[(size_t)b * LL * 32];
    float* yb = &ysum[(size_t)b * LL * 128];

    int pj[CS];
#pragma unroll
    for (int i = 0; i < CS; ++i) {
        const int l = l0a + i;
        pj[i] = (l % HHH) * WWW + (l / HHH);
    }
    float xv[CS];
#pragma unroll
    for (int i = 0; i < CS; ++i) xv[i] = xcb[(size_t)pj[i] * 128 + d];

    float y[CS];

    {
        const float dtw0 = dtw_g[(2 * 128 + d) * 4 + 0];
        const float dtw1 = dtw_g[(2 * 128 + d) * 4 + 1];
        const float dtw2 = dtw_g[(2 * 128 + d) * 4 + 2];
        const float dtw3 = dtw_g[(2 * 128 + d) * 4 + 3];
        const float dtb  = dtb_g[2 * 128 + d];
        const float Aneg = -__expf(alog[2 * 128 + d]);
        const float Dd   = ds_g[2 * 128 + d];
        float h = H0[((size_t)bk2 * NCH + c) * 128 + d];
#pragma unroll
        for (int i = 0; i < CS; ++i) {
            const float* row = &base[(size_t)pj[i] * 32 + 16];
            const float draw = fmaf(row[0], dtw0, fmaf(row[1], dtw1,
                               fmaf(row[2], dtw2, fmaf(row[3], dtw3, dtb))));
            const float dt  = softplus_(draw);
            const float dA  = __expf(dt * Aneg);
            h = fmaf(dA, h, dt * row[4] * xv[i]);
            y[i] = fmaf(h, row[5], Dd * xv[i]);
        }
    }
    {
        const float dtw0 = dtw_g[(3 * 128 + d) * 4 + 0];
        const float dtw1 = dtw_g[(3 * 128 + d) * 4 + 1];
        const float dtw2 = dtw_g[(3 * 128 + d) * 4 + 2];
        const float dtw3 = dtw_g[(3 * 128 + d) * 4 + 3];
        const float dtb  = dtb_g[3 * 128 + d];
        const float Aneg = -__expf(alog[3 * 128 + d]);
        const float Dd   = ds_g[3 * 128 + d];
        float h = H0[((size_t)bk3 * NCH + c2) * 128 + d];
#pragma unroll
        for (int i = 0; i < CS; ++i) {
            const int j = CS - 1 - i;
            const float* row = &base[(size_t)pj[j] * 32 + 24];
            const float draw = fmaf(row[0], dtw0, fmaf(row[1], dtw1,
                               fmaf(row[2], dtw2, fmaf(row[3], dtw3, dtb))));
            const float dt  = softplus_(draw);
            const float dA  = __expf(dt * Aneg);
            h = fmaf(dA, h, dt * row[4] * xv[j]);
            y[j] += fmaf(h, row[5], Dd * xv[j]);
        }
    }
#pragma unroll
    for (int i = 0; i < CS; ++i)
        atomicAdd(&yb[(size_t)pj[i] * 128 + d], y[i]);
}

// ---------------- Kernel E: LayerNorm + gate + spatial mean ----------------
__global__ __launch_bounds__(256) void k_final(const float* __restrict__ ysum,
                                               const float* __restrict__ zs,
                                               const float* __restrict__ onw,
                                               const float* __restrict__ onb,
                                               float* __restrict__ out)
{
    const int wid  = threadIdx.x >> 6;
    const int lane = threadIdx.x & 63;
    const int b     = blockIdx.x / 49;
    const int chunk = blockIdx.x % 49;
    const int pbase = chunk * 64 + wid * 16;

    const float w0 = onw[lane], w1 = onw[lane + 64];
    const float b0 = onb[lane], b1 = onb[lane + 64];

    float acc0 = 0.0f, acc1 = 0.0f;
    for (int i = 0; i < 16; ++i) {
        const int p = pbase + i;
        const float v0 = ysum[((size_t)b * LL + p) * 128 + lane];
        const float v1 = ysum[((size_t)b * LL + p) * 128 + lane + 64];
        float s = v0 + v1;
#pragma unroll
        for (int off = 32; off >= 1; off >>= 1) s += __shfl_xor(s, off, 64);
        const float mu = s * (1.0f / 128.0f);
        const float d0 = v0 - mu, d1 = v1 - mu;
        float sq = d0 * d0 + d1 * d1;
#pragma unroll
        for (int off = 32; off >= 1; off >>= 1) sq += __shfl_xor(sq, off, 64);
        const float rstd = rsqrtf(sq * (1.0f / 128.0f) + 1e-5f);
        const float yn0 = fmaf(d0 * rstd, w0, b0);
        const float yn1 = fmaf(d1 * rstd, w1, b1);
        const float g0 = zs[((size_t)b * LL + p) * 128 + lane];
        const float g1 = zs[((size_t)b * LL + p) * 128 + lane + 64];
        acc0 = fmaf(yn0, g0, acc0);
        acc1 = fmaf(yn1, g1, acc1);
    }
    atomicAdd(&out[b * 128 + lane],      acc0 * (1.0f / (float)LL));
    atomicAdd(&out[b * 128 + lane + 64], acc1 * (1.0f / (float)LL));
}

extern "C" void kernel_launch(void* const* d_in, const int* in_sizes, int n_in,
                              void* d_out, int out_size, void* d_ws, size_t ws_size,
                              hipStream_t stream)
{
    const float* x     = (const float*)d_in[0];
    const float* ipw   = (const float*)d_in[1];
    const float* cw    = (const float*)d_in[2];
    const float* cb    = (const float*)d_in[3];
    const float* xpw   = (const float*)d_in[4];
    const float* dtw   = (const float*)d_in[5];
    const float* dtb   = (const float*)d_in[6];
    const float* alog  = (const float*)d_in[7];
    const float* dsg   = (const float*)d_in[8];
    const float* onw   = (const float*)d_in[9];
    const float* onb   = (const float*)d_in[10];
    float* out = (float*)d_out;

    float* ws   = (float*)d_ws;
    float* xi   = ws + OFF_XI;     // becomes ysum after conv
    float* zs   = ws + OFF_ZS;
    float* xc   = ws + OFF_XC;
    float* xdn  = ws + OFF_XDN;
    float* Pa   = ws + OFF_PA;
    float* Hl   = ws + OFF_HL;
    float* H0   = ws + OFF_H0;
    float* ysum = xi;
    // Whi/Wlo live in the (not-yet-written) xc region during inproj
    short* Whi = (short*)(ws + OFF_XC);
    short* Wlo = (short*)(ws + OFF_XC + 16384);

    hipMemsetAsync(out, 0, (size_t)out_size * 4, stream);

    k_wsplit<<<128, 256, 0, stream>>>(ipw, Whi, Wlo);
    k_inproj<<<784, 256, 0, stream>>>(x, Whi, Wlo, xi, zs);

    const size_t totB = (size_t)BB * LL * DI_;
    k_conv<<<(int)((totB + 255) / 256), 256, 0, stream>>>(xi, cw, cb, xc);

    k_projN<<<BB * 49, 256, 0, stream>>>(xc, xpw, xdn);

    k_scan1m<<<2 * BB * NCH, 128, 0, stream>>>(xc, xdn, dtw, dtb, alog, Pa, Hl);
    k_scan2<<<BB * KK, 128, 0, stream>>>(Pa, Hl, H0);
    k_scan3a<<<BB * NCH, 128, 0, stream>>>(xc, xdn, dtw, dtb, alog, dsg, H0, ysum);
    k_scan3b<<<BB * NCH, 128, 0, stream>>>(xc, xdn, dtw, dtb, alog, dsg, H0, ysum);

    k_final<<<BB * 49, 256, 0, stream>>>(ysum, zs, onw, onb, out);
}

// Round 6
// 256.273 us; speedup vs baseline: 7.1733x; 1.2086x over previous
//
#include <hip/hip_runtime.h>
#include <math.h>

#define BB   16
#define HHH  56
#define WWW  56
#define LL   3136      // 56*56
#define DI_  128
#define KK   4
#define NCH  98        // chunks per (b,k)
#define CS   32        // chunk size; NCH*CS == LL

// workspace layout (floats)
#define OFF_XI   ((size_t)0)           // B*L*DI ; reused as YSUM
#define OFF_ZS   ((size_t)6422528)
#define OFF_XC   ((size_t)12845056)    // xc; also hosts Whi/Wlo BEFORE k_conv writes it
#define OFF_XDN  ((size_t)19267584)    // B*L*32
#define OFF_PA   ((size_t)20873216)
#define OFF_HL   ((size_t)21676032)
#define OFF_H0   ((size_t)22478848)
#define OFF_CWT  ((size_t)23281664)    // 9*128 transposed conv weights

typedef short s16x8 __attribute__((ext_vector_type(8)));
typedef float f32x4 __attribute__((ext_vector_type(4)));

__device__ __forceinline__ float sigmoidf_(float x) { return 1.0f / (1.0f + __expf(-x)); }
__device__ __forceinline__ float softplus_(float x) {
    return fmaxf(x, 0.0f) + __logf(1.0f + __expf(-fabsf(x)));
}

// split f into bf16 hi/lo (RNE)
__device__ __forceinline__ void bf16split(float f, short* hi, short* lo) {
    unsigned u = __float_as_uint(f);
    unsigned r = u + 0x7FFFu + ((u >> 16) & 1u);
    *hi = (short)(r >> 16);
    float hf = __uint_as_float(r & 0xFFFF0000u);
    float l  = f - hf;
    unsigned u2 = __float_as_uint(l);
    unsigned r2 = u2 + 0x7FFFu + ((u2 >> 16) & 1u);
    *lo = (short)(r2 >> 16);
}

// ---------------- Kernel W: pre-split in_proj weights + transpose conv weights ----------------
__global__ __launch_bounds__(256) void k_wsplit(const float* __restrict__ Wp,
                                                const float* __restrict__ cw,
                                                short* __restrict__ Whi,
                                                short* __restrict__ Wlo,
                                                float* __restrict__ cwT)
{
    const int idx = blockIdx.x * 256 + threadIdx.x;
    if (idx < 256 * 128) {
        short h, l;
        bf16split(Wp[idx], &h, &l);
        Whi[idx] = h;
        Wlo[idx] = l;
    }
    if (idx < 9 * 128) {
        const int t = idx >> 7;
        const int d = idx & 127;
        cwT[t * 128 + d] = cw[d * 9 + t];
    }
}

// ---------------- Kernel A: in_proj GEMM via bf16x3 MFMA ----------------
#define APAD 136   // 128 + 8 shorts row pad
__global__ __launch_bounds__(256) void k_inproj(const float* __restrict__ x,
                                                const short* __restrict__ Whi,
                                                const short* __restrict__ Wlo,
                                                float* __restrict__ xi,
                                                float* __restrict__ zs)
{
    __shared__ short Ahi[64 * APAD];
    __shared__ short Alo[64 * APAD];
    const int tid  = threadIdx.x;
    const int row0 = blockIdx.x * 64;

#pragma unroll
    for (int i = 0; i < 8; ++i) {
        const int idx4 = i * 256 + tid;
        const int row  = idx4 >> 5;
        const int k4   = (idx4 & 31) * 4;
        float4 v = *(const float4*)&x[(size_t)(row0 + row) * 128 + k4];
        const float f[4] = {v.x, v.y, v.z, v.w};
#pragma unroll
        for (int j = 0; j < 4; ++j) {
            short h, l;
            bf16split(f[j], &h, &l);
            Ahi[row * APAD + k4 + j] = h;
            Alo[row * APAD + k4 + j] = l;
        }
    }
    __syncthreads();

    const int w    = tid >> 6;
    const int lane = tid & 63;
    const int lr   = lane & 15;
    const int lk   = (lane >> 4) * 8;

    for (int cg = 0; cg < 4; ++cg) {
        const int col0 = cg * 64 + w * 16;
        s16x8 bhi[4], blo[4];
#pragma unroll
        for (int ks = 0; ks < 4; ++ks) {
            const size_t wo = (size_t)(col0 + lr) * 128 + ks * 32 + lk;
            bhi[ks] = *(const s16x8*)&Whi[wo];
            blo[ks] = *(const s16x8*)&Wlo[wo];
        }
#pragma unroll
        for (int rt = 0; rt < 4; ++rt) {
            f32x4 acc = {0.f, 0.f, 0.f, 0.f};
#pragma unroll
            for (int ks = 0; ks < 4; ++ks) {
                const int ao = (rt * 16 + lr) * APAD + ks * 32 + lk;
                s16x8 ahi = *(const s16x8*)&Ahi[ao];
                s16x8 alo = *(const s16x8*)&Alo[ao];
                acc = __builtin_amdgcn_mfma_f32_16x16x32_bf16(alo, bhi[ks], acc, 0, 0, 0);
                acc = __builtin_amdgcn_mfma_f32_16x16x32_bf16(ahi, blo[ks], acc, 0, 0, 0);
                acc = __builtin_amdgcn_mfma_f32_16x16x32_bf16(ahi, bhi[ks], acc, 0, 0, 0);
            }
            const int col = col0 + lr;
#pragma unroll
            for (int j = 0; j < 4; ++j) {
                const size_t row = row0 + rt * 16 + (lane >> 4) * 4 + j;
                const float v = acc[j];
                if (col < 128) {
                    xi[row * 128 + col] = v;
                } else {
                    zs[row * 128 + (col - 128)] = v * sigmoidf_(v);
                }
            }
        }
    }
}

// ---------------- Kernel B: depthwise conv, float4 x 2 rows, XCD-swizzled ----------------
// grid: 3136 blocks x 256 thr; thread = (b, h-pair, w, d-group)
__global__ __launch_bounds__(256) void k_conv4(const float* __restrict__ xi,
                                               const float* __restrict__ cwT,
                                               const float* __restrict__ cb,
                                               float* __restrict__ xc)
{
    const int wid = (blockIdx.x & 7) * 392 + (blockIdx.x >> 3);   // 3136 = 8*392
    const int idx = wid * 256 + threadIdx.x;
    const int d0  = (idx & 31) * 4;
    int rest = idx >> 5;
    const int w  = rest % WWW;
    rest /= WWW;
    const int hp = rest % 28;
    const int b  = rest / 28;
    const int h0 = hp * 2;

    float4 wt[9];
#pragma unroll
    for (int t = 0; t < 9; ++t) wt[t] = *(const float4*)&cwT[t * 128 + d0];
    const float4 bias = *(const float4*)&cb[d0];

    float4 a0 = bias, a1 = bias;
    const float* base = &xi[(size_t)b * LL * 128 + d0];
#pragma unroll
    for (int dr = -1; dr <= 2; ++dr) {
        const int hh = h0 + dr;
        if (hh < 0 || hh >= HHH) continue;
#pragma unroll
        for (int dc = -1; dc <= 1; ++dc) {
            const int ww = w + dc;
            if (ww < 0 || ww >= WWW) continue;
            const float4 v = *(const float4*)&base[(size_t)(hh * WWW + ww) * 128];
            if (dr <= 1) {
                const float4 wv = wt[(dr + 1) * 3 + (dc + 1)];
                a0.x = fmaf(v.x, wv.x, a0.x);
                a0.y = fmaf(v.y, wv.y, a0.y);
                a0.z = fmaf(v.z, wv.z, a0.z);
                a0.w = fmaf(v.w, wv.w, a0.w);
            }
            if (dr >= 0) {
                const float4 wv = wt[dr * 3 + (dc + 1)];
                a1.x = fmaf(v.x, wv.x, a1.x);
                a1.y = fmaf(v.y, wv.y, a1.y);
                a1.z = fmaf(v.z, wv.z, a1.z);
                a1.w = fmaf(v.w, wv.w, a1.w);
            }
        }
    }
    float4 o0, o1;
    o0.x = a0.x * sigmoidf_(a0.x); o0.y = a0.y * sigmoidf_(a0.y);
    o0.z = a0.z * sigmoidf_(a0.z); o0.w = a0.w * sigmoidf_(a0.w);
    o1.x = a1.x * sigmoidf_(a1.x); o1.y = a1.y * sigmoidf_(a1.y);
    o1.z = a1.z * sigmoidf_(a1.z); o1.w = a1.w * sigmoidf_(a1.w);
    *(float4*)&xc[((size_t)b * LL + h0 * WWW + w) * 128 + d0]       = o0;
    *(float4*)&xc[((size_t)b * LL + (h0 + 1) * WWW + w) * 128 + d0] = o1;
}

// ---------------- Kernel C: projection in natural order ----------------
__global__ __launch_bounds__(256) void k_projN(const float* __restrict__ xc,
                                               const float* __restrict__ xpw,
                                               float* __restrict__ xdn)
{
    __shared__ float xs[64 * 129];
    __shared__ float wl[24 * 128];
    const int tid = threadIdx.x;
    const int b   = blockIdx.x / 49;
    const int p0  = (blockIdx.x % 49) * 64;

    for (int i = tid; i < 24 * 128; i += 256) wl[i] = xpw[i];

#pragma unroll
    for (int i = 0; i < 8; ++i) {
        const int idx4 = i * 256 + tid;
        const int row  = idx4 >> 5;
        const int d4   = (idx4 & 31) * 4;
        float4 v = *(const float4*)&xc[((size_t)b * LL + p0 + row) * 128 + d4];
        xs[row * 129 + d4 + 0] = v.x;
        xs[row * 129 + d4 + 1] = v.y;
        xs[row * 129 + d4 + 2] = v.z;
        xs[row * 129 + d4 + 3] = v.w;
    }
    __syncthreads();

    const int ks   = tid >> 6;
    const int lane = tid & 63;
    float a0 = 0.f, a1 = 0.f, a2 = 0.f, a3 = 0.f, a4 = 0.f, a5 = 0.f;
    const float* wb = &wl[ks * 6 * 128];
#pragma unroll 4
    for (int d = 0; d < 128; ++d) {
        const float xv = xs[lane * 129 + d];
        a0 = fmaf(xv, wb[0 * 128 + d], a0);
        a1 = fmaf(xv, wb[1 * 128 + d], a1);
        a2 = fmaf(xv, wb[2 * 128 + d], a2);
        a3 = fmaf(xv, wb[3 * 128 + d], a3);
        a4 = fmaf(xv, wb[4 * 128 + d], a4);
        a5 = fmaf(xv, wb[5 * 128 + d], a5);
    }
    float* o = &xdn[((size_t)(b * LL + p0 + lane)) * 32 + ks * 8];
    o[0] = a0; o[1] = a1; o[2] = a2; o[3] = a3; o[4] = a4; o[5] = a5;
}

// ---------------- Scan pass 1 (merged direction pairs, LDS-staged rows) ----------------
// grid: 2*BB*NCH; mode 0 -> dirs {0,1} (reads xdn[...0:16)), mode 1 -> dirs {2,3} ([16:32))
__global__ __launch_bounds__(128) void k_scan1m(const float* __restrict__ xc,
                                                const float* __restrict__ xdn,
                                                const float* __restrict__ dtw_g,
                                                const float* __restrict__ dtb_g,
                                                const float* __restrict__ alog,
                                                float* __restrict__ Pa,
                                                float* __restrict__ Hl)
{
    __shared__ float xds[CS * 16];
    const int mode = blockIdx.x / (BB * NCH);
    const int rem  = blockIdx.x % (BB * NCH);
    const int b = rem / NCH;
    const int c = rem % NCH;
    const int d = threadIdx.x;
    const int c2 = NCH - 1 - c;
    const int l0a = c * CS;
    const int kA = mode * 2;
    const int kB = kA + 1;
    const int bkA = b * 4 + kA, bkB = b * 4 + kB;

    const float* xcb  = &xc[(size_t)b * LL * 128];
    const float* base = &xdn[(size_t)b * LL * 32];

    // cooperative stage: 32 rows x 16 floats (half-row for this mode)
    {
        const int row = d >> 2;
        const int q   = (d & 3) * 4;
        int prow;
        if (mode == 0) prow = l0a + row;
        else { const int l = l0a + row; prow = (l % HHH) * WWW + (l / HHH); }
        *(float4*)&xds[row * 16 + q] = *(const float4*)&base[(size_t)prow * 32 + mode * 16 + q];
    }
    __syncthreads();

    int pj[CS];
    if (mode == 0) {
#pragma unroll
        for (int i = 0; i < CS; ++i) pj[i] = l0a + i;
    } else {
#pragma unroll
        for (int i = 0; i < CS; ++i) {
            const int l = l0a + i;
            pj[i] = (l % HHH) * WWW + (l / HHH);
        }
    }
    float xv[CS];
#pragma unroll
    for (int i = 0; i < CS; ++i) xv[i] = xcb[(size_t)pj[i] * 128 + d];

    // dir kA: forward, row offset 0
    {
        const float dtw0 = dtw_g[(kA * 128 + d) * 4 + 0];
        const float dtw1 = dtw_g[(kA * 128 + d) * 4 + 1];
        const float dtw2 = dtw_g[(kA * 128 + d) * 4 + 2];
        const float dtw3 = dtw_g[(kA * 128 + d) * 4 + 3];
        const float dtb  = dtb_g[kA * 128 + d];
        const float Aneg = -__expf(alog[kA * 128 + d]);
        float P = 1.0f, h = 0.0f;
#pragma unroll
        for (int i = 0; i < CS; ++i) {
            const float* row = &xds[i * 16];
            const float draw = fmaf(row[0], dtw0, fmaf(row[1], dtw1,
                               fmaf(row[2], dtw2, fmaf(row[3], dtw3, dtb))));
            const float dt  = softplus_(draw);
            const float dA  = __expf(dt * Aneg);
            P *= dA;
            h = fmaf(dA, h, dt * row[4] * xv[i]);
        }
        Pa[((size_t)bkA * NCH + c) * 128 + d] = P;
        Hl[((size_t)bkA * NCH + c) * 128 + d] = h;
    }
    // dir kB: reversed, row offset 8
    {
        const float dtw0 = dtw_g[(kB * 128 + d) * 4 + 0];
        const float dtw1 = dtw_g[(kB * 128 + d) * 4 + 1];
        const float dtw2 = dtw_g[(kB * 128 + d) * 4 + 2];
        const float dtw3 = dtw_g[(kB * 128 + d) * 4 + 3];
        const float dtb  = dtb_g[kB * 128 + d];
        const float Aneg = -__expf(alog[kB * 128 + d]);
        float P = 1.0f, h = 0.0f;
#pragma unroll
        for (int i = 0; i < CS; ++i) {
            const int j = CS - 1 - i;
            const float* row = &xds[j * 16 + 8];
            const float draw = fmaf(row[0], dtw0, fmaf(row[1], dtw1,
                               fmaf(row[2], dtw2, fmaf(row[3], dtw3, dtb))));
            const float dt  = softplus_(draw);
            const float dA  = __expf(dt * Aneg);
            P *= dA;
            h = fmaf(dA, h, dt * row[4] * xv[j]);
        }
        Pa[((size_t)bkB * NCH + c2) * 128 + d] = P;
        Hl[((size_t)bkB * NCH + c2) * 128 + d] = h;
    }
}

// ---------------- Scan pass 2: combine chunk summaries ----------------
__global__ __launch_bounds__(128) void k_scan2(const float* __restrict__ Pa,
                                               const float* __restrict__ Hl,
                                               float* __restrict__ H0)
{
    const int bk = blockIdx.x;
    const int d  = threadIdx.x;
    float h = 0.0f;
#pragma unroll 7
    for (int c = 0; c < NCH; ++c) {
        const size_t o = ((size_t)bk * NCH + c) * 128 + d;
        H0[o] = h;
        h = fmaf(Pa[o], h, Hl[o]);
    }
}

// ---------------- Scan pass 3a: dirs 0+1, LDS-staged, plain store ----------------
__global__ __launch_bounds__(128) void k_scan3a(const float* __restrict__ xc,
                                                const float* __restrict__ xdn,
                                                const float* __restrict__ dtw_g,
                                                const float* __restrict__ dtb_g,
                                                const float* __restrict__ alog,
                                                const float* __restrict__ ds_g,
                                                const float* __restrict__ H0,
                                                float* __restrict__ ysum)
{
    __shared__ float xds[CS * 16];
    const int b = blockIdx.x / NCH;
    const int c = blockIdx.x % NCH;
    const int d = threadIdx.x;
    const int c2 = NCH - 1 - c;
    const int bk0 = b * 4 + 0, bk1 = b * 4 + 1;
    const int l0a = c * CS;

    const float* xcb  = &xc[(size_t)b * LL * 128];
    const float* base = &xdn[(size_t)b * LL * 32];
    float* yb = &ysum[(size_t)b * LL * 128];

    {
        const int row = d >> 2;
        const int q   = (d & 3) * 4;
        *(float4*)&xds[row * 16 + q] = *(const float4*)&base[(size_t)(l0a + row) * 32 + q];
    }
    __syncthreads();

    float xv[CS];
#pragma unroll
    for (int i = 0; i < CS; ++i) xv[i] = xcb[(size_t)(l0a + i) * 128 + d];

    float y[CS];

    {
        const float dtw0 = dtw_g[(0 * 128 + d) * 4 + 0];
        const float dtw1 = dtw_g[(0 * 128 + d) * 4 + 1];
        const float dtw2 = dtw_g[(0 * 128 + d) * 4 + 2];
        const float dtw3 = dtw_g[(0 * 128 + d) * 4 + 3];
        const float dtb  = dtb_g[0 * 128 + d];
        const float Aneg = -__expf(alog[0 * 128 + d]);
        const float Dd   = ds_g[0 * 128 + d];
        float h = H0[((size_t)bk0 * NCH + c) * 128 + d];
#pragma unroll
        for (int i = 0; i < CS; ++i) {
            const float* row = &xds[i * 16];
            const float draw = fmaf(row[0], dtw0, fmaf(row[1], dtw1,
                               fmaf(row[2], dtw2, fmaf(row[3], dtw3, dtb))));
            const float dt  = softplus_(draw);
            const float dA  = __expf(dt * Aneg);
            h = fmaf(dA, h, dt * row[4] * xv[i]);
            y[i] = fmaf(h, row[5], Dd * xv[i]);
        }
    }
    {
        const float dtw0 = dtw_g[(1 * 128 + d) * 4 + 0];
        const float dtw1 = dtw_g[(1 * 128 + d) * 4 + 1];
        const float dtw2 = dtw_g[(1 * 128 + d) * 4 + 2];
        const float dtw3 = dtw_g[(1 * 128 + d) * 4 + 3];
        const float dtb  = dtb_g[1 * 128 + d];
        const float Aneg = -__expf(alog[1 * 128 + d]);
        const float Dd   = ds_g[1 * 128 + d];
        float h = H0[((size_t)bk1 * NCH + c2) * 128 + d];
#pragma unroll
        for (int i = 0; i < CS; ++i) {
            const int j = CS - 1 - i;
            const float* row = &xds[j * 16 + 8];
            const float draw = fmaf(row[0], dtw0, fmaf(row[1], dtw1,
                               fmaf(row[2], dtw2, fmaf(row[3], dtw3, dtb))));
            const float dt  = softplus_(draw);
            const float dA  = __expf(dt * Aneg);
            h = fmaf(dA, h, dt * row[4] * xv[j]);
            y[j] += fmaf(h, row[5], Dd * xv[j]);
        }
    }
#pragma unroll
    for (int i = 0; i < CS; ++i)
        yb[(size_t)(l0a + i) * 128 + d] = y[i];
}

// ---------------- Scan pass 3b: dirs 2+3, LDS-staged, atomic add ----------------
__global__ __launch_bounds__(128) void k_scan3b(const float* __restrict__ xc,
                                                const float* __restrict__ xdn,
                                                const float* __restrict__ dtw_g,
                                                const float* __restrict__ dtb_g,
                                                const float* __restrict__ alog,
                                                const float* __restrict__ ds_g,
                                                const float* __restrict__ H0,
                                                float* __restrict__ ysum)
{
    __shared__ float xds[CS * 16];
    const int b = blockIdx.x / NCH;
    const int c = blockIdx.x % NCH;
    const int d = threadIdx.x;
    const int c2 = NCH - 1 - c;
    const int bk2 = b * 4 + 2, bk3 = b * 4 + 3;
    const int l0a = c * CS;

    const float* xcb  = &xc[(size_t)b * LL * 128];
    const float* base = &xdn[(size_t)b * LL * 32];
    float* yb = &ysum[(size_t)b * LL * 128];

    {
        const int row = d >> 2;
        const int q   = (d & 3) * 4;
        const int l   = l0a + row;
        const int prow = (l % HHH) * WWW + (l / HHH);
        *(float4*)&xds[row * 16 + q] = *(const float4*)&base[(size_t)prow * 32 + 16 + q];
    }
    __syncthreads();

    int pj[CS];
#pragma unroll
    for (int i = 0; i < CS; ++i) {
        const int l = l0a + i;
        pj[i] = (l % HHH) * WWW + (l / HHH);
    }
    float xv[CS];
#pragma unroll
    for (int i = 0; i < CS; ++i) xv[i] = xcb[(size_t)pj[i] * 128 + d];

    float y[CS];

    {
        const float dtw0 = dtw_g[(2 * 128 + d) * 4 + 0];
        const float dtw1 = dtw_g[(2 * 128 + d) * 4 + 1];
        const float dtw2 = dtw_g[(2 * 128 + d) * 4 + 2];
        const float dtw3 = dtw_g[(2 * 128 + d) * 4 + 3];
        const float dtb  = dtb_g[2 * 128 + d];
        const float Aneg = -__expf(alog[2 * 128 + d]);
        const float Dd   = ds_g[2 * 128 + d];
        float h = H0[((size_t)bk2 * NCH + c) * 128 + d];
#pragma unroll
        for (int i = 0; i < CS; ++i) {
            const float* row = &xds[i * 16];
            const float draw = fmaf(row[0], dtw0, fmaf(row[1], dtw1,
                               fmaf(row[2], dtw2, fmaf(row[3], dtw3, dtb))));
            const float dt  = softplus_(draw);
            const float dA  = __expf(dt * Aneg);
            h = fmaf(dA, h, dt * row[4] * xv[i]);
            y[i] = fmaf(h, row[5], Dd * xv[i]);
        }
    }
    {
        const float dtw0 = dtw_g[(3 * 128 + d) * 4 + 0];
        const float dtw1 = dtw_g[(3 * 128 + d) * 4 + 1];
        const float dtw2 = dtw_g[(3 * 128 + d) * 4 + 2];
        const float dtw3 = dtw_g[(3 * 128 + d) * 4 + 3];
        const float dtb  = dtb_g[3 * 128 + d];
        const float Aneg = -__expf(alog[3 * 128 + d]);
        const float Dd   = ds_g[3 * 128 + d];
        float h = H0[((size_t)bk3 * NCH + c2) * 128 + d];
#pragma unroll
        for (int i = 0; i < CS; ++i) {
            const int j = CS - 1 - i;
            const float* row = &xds[j * 16 + 8];
            const float draw = fmaf(row[0], dtw0, fmaf(row[1], dtw1,
                               fmaf(row[2], dtw2, fmaf(row[3], dtw3, dtb))));
            const float dt  = softplus_(draw);
            const float dA  = __expf(dt * Aneg);
            h = fmaf(dA, h, dt * row[4] * xv[j]);
            y[j] += fmaf(h, row[5], Dd * xv[j]);
        }
    }
#pragma unroll
    for (int i = 0; i < CS; ++i)
        atomicAdd(&yb[(size_t)pj[i] * 128 + d], y[i]);
}

// ---------------- Kernel E: LayerNorm + gate + spatial mean ----------------
__global__ __launch_bounds__(256) void k_final(const float* __restrict__ ysum,
                                               const float* __restrict__ zs,
                                               const float* __restrict__ onw,
                                               const float* __restrict__ onb,
                                               float* __restrict__ out)
{
    const int wid  = threadIdx.x >> 6;
    const int lane = threadIdx.x & 63;
    const int b     = blockIdx.x / 49;
    const int chunk = blockIdx.x % 49;
    const int pbase = chunk * 64 + wid * 16;

    const float w0 = onw[lane], w1 = onw[lane + 64];
    const float b0 = onb[lane], b1 = onb[lane + 64];

    float acc0 = 0.0f, acc1 = 0.0f;
    for (int i = 0; i < 16; ++i) {
        const int p = pbase + i;
        const float v0 = ysum[((size_t)b * LL + p) * 128 + lane];
        const float v1 = ysum[((size_t)b * LL + p) * 128 + lane + 64];
        float s = v0 + v1;
#pragma unroll
        for (int off = 32; off >= 1; off >>= 1) s += __shfl_xor(s, off, 64);
        const float mu = s * (1.0f / 128.0f);
        const float d0 = v0 - mu, d1 = v1 - mu;
        float sq = d0 * d0 + d1 * d1;
#pragma unroll
        for (int off = 32; off >= 1; off >>= 1) sq += __shfl_xor(sq, off, 64);
        const float rstd = rsqrtf(sq * (1.0f / 128.0f) + 1e-5f);
        const float yn0 = fmaf(d0 * rstd, w0, b0);
        const float yn1 = fmaf(d1 * rstd, w1, b1);
        const float g0 = zs[((size_t)b * LL + p) * 128 + lane];
        const float g1 = zs[((size_t)b * LL + p) * 128 + lane + 64];
        acc0 = fmaf(yn0, g0, acc0);
        acc1 = fmaf(yn1, g1, acc1);
    }
    atomicAdd(&out[b * 128 + lane],      acc0 * (1.0f / (float)LL));
    atomicAdd(&out[b * 128 + lane + 64], acc1 * (1.0f / (float)LL));
}

extern "C" void kernel_launch(void* const* d_in, const int* in_sizes, int n_in,
                              void* d_out, int out_size, void* d_ws, size_t ws_size,
                              hipStream_t stream)
{
    const float* x     = (const float*)d_in[0];
    const float* ipw   = (const float*)d_in[1];
    const float* cw    = (const float*)d_in[2];
    const float* cb    = (const float*)d_in[3];
    const float* xpw   = (const float*)d_in[4];
    const float* dtw   = (const float*)d_in[5];
    const float* dtb   = (const float*)d_in[6];
    const float* alog  = (const float*)d_in[7];
    const float* dsg   = (const float*)d_in[8];
    const float* onw   = (const float*)d_in[9];
    const float* onb   = (const float*)d_in[10];
    float* out = (float*)d_out;

    float* ws   = (float*)d_ws;
    float* xi   = ws + OFF_XI;     // becomes ysum
    float* zs   = ws + OFF_ZS;
    float* xc   = ws + OFF_XC;
    float* xdn  = ws + OFF_XDN;
    float* Pa   = ws + OFF_PA;
    float* Hl   = ws + OFF_HL;
    float* H0   = ws + OFF_H0;
    float* cwT  = ws + OFF_CWT;
    float* ysum = xi;
    short* Whi = (short*)(ws + OFF_XC);
    short* Wlo = (short*)(ws + OFF_XC + 16384);

    hipMemsetAsync(out, 0, (size_t)out_size * 4, stream);

    k_wsplit<<<128, 256, 0, stream>>>(ipw, cw, Whi, Wlo, cwT);
    k_inproj<<<784, 256, 0, stream>>>(x, Whi, Wlo, xi, zs);

    k_conv4<<<3136, 256, 0, stream>>>(xi, cwT, cb, xc);

    k_projN<<<BB * 49, 256, 0, stream>>>(xc, xpw, xdn);

    k_scan1m<<<2 * BB * NCH, 128, 0, stream>>>(xc, xdn, dtw, dtb, alog, Pa, Hl);
    k_scan2<<<BB * KK, 128, 0, stream>>>(Pa, Hl, H0);
    k_scan3a<<<BB * NCH, 128, 0, stream>>>(xc, xdn, dtw, dtb, alog, dsg, H0, ysum);
    k_scan3b<<<BB * NCH, 128, 0, stream>>>(xc, xdn, dtw, dtb, alog, dsg, H0, ysum);

    k_final<<<BB * 49, 256, 0, stream>>>(ysum, zs, onw, onb, out);
}